// Round 13
// baseline (446.902 us; speedup 1.0000x reference)
//
#include <hip/hip_runtime.h>
#include <hip/hip_bf16.h>

// DistGAT: 3-layer GAT, N=50000 nodes, E=800000 edges.
// R13: fuse layer-3 aggregation + tail GEMM (k_fuse3). R12's aggrZ3 (57us) was
//      at its own byte-roofline with 150MB of it being the zf write that
//      mtail3 (~45us) immediately re-read: a 300MB HBM round trip.
//  - 512-thr block, 32 nodes: phase 1 = aggrZ3 edge loop -> z in LDS
//    [32][772] f32 (98.8KB, stride-772 => <=2-way banks); phase 2 = 32x64 MFMA
//    tile, K=896, z hi/lo bf16-split on the fly from LDS (same pk2 numerics),
//    B frags straight from L2-resident BT2. zf buffer deleted.
// Everything else identical to R12.

#define NODES 50000
#define EDGES 800000
#define NEG 0.2f

typedef __attribute__((ext_vector_type(8))) short bh8;
typedef __attribute__((ext_vector_type(4))) float f4;

__device__ __forceinline__ float leaky(float e) { return e > 0.f ? e : NEG * e; }
__device__ __forceinline__ float blo(unsigned u) { return __uint_as_float(u << 16); }
__device__ __forceinline__ float bhi(unsigned u) { return __uint_as_float(u & 0xffff0000u); }
__device__ __forceinline__ unsigned f2bf(float f) {  // RNE, low 16 bits valid
    unsigned u = __float_as_uint(f);
    return (u + 0x7fffu + ((u >> 16) & 1u)) >> 16;
}

// swizzled byte offset in a [rows][128-bf16] LDS tile (row stride 256 B)
#define SW(row, bc) (((row) << 8) + ((bc) ^ (((row) & 7) << 4)))

// ---------------------------------------------------------------- prep
__global__ void k_cast(const float* __restrict__ in, unsigned short* __restrict__ outb, int n4) {
    int gid = blockIdx.x * blockDim.x + threadIdx.x;
    if (gid >= n4) return;
    float4 v = *reinterpret_cast<const float4*>(in + (size_t)gid * 4);
    unsigned u0 = f2bf(v.x) | (f2bf(v.y) << 16);
    unsigned u1 = f2bf(v.z) | (f2bf(v.w) << 16);
    *reinterpret_cast<uint2*>(outb + (size_t)gid * 4) = make_uint2(u0, u1);
}

__global__ void k_prepw(const float* __restrict__ W, unsigned short* __restrict__ WT, int F) {
    int gid = blockIdx.x * blockDim.x + threadIdx.x;
    if (gid >= 128 * F) return;
    int k = gid / F, f = gid - k * F;
    WT[(size_t)f * 128 + k] = (unsigned short)f2bf(W[gid]);
}

__global__ void k_prep_bt2(const float* __restrict__ W3, const float* __restrict__ Wres3,
                           unsigned short* __restrict__ BT2) {
    int gid = blockIdx.x * blockDim.x + threadIdx.x;
    if (gid >= 64 * 896) return;
    int d = gid / 896, k = gid - d * 896;
    float v;
    if (k < 768) {
        v = W3[(size_t)(k & 127) * 384 + (k >> 7) * 64 + d];
    } else {
        int kr = k - 768;
        v = 0.f;
#pragma unroll
        for (int h = 0; h < 6; ++h) v += Wres3[(size_t)kr * 384 + h * 64 + d];
    }
    BT2[(size_t)d * 896 + k] = (unsigned short)f2bf(v);
}

__global__ void k_prep_alr3(const float* __restrict__ W3, const float* __restrict__ al3,
                            const float* __restrict__ ar3, float* __restrict__ al3c,
                            float* __restrict__ ar3c) {
    int gid = blockIdx.x * blockDim.x + threadIdx.x;
    if (gid >= 1536) return;
    int g = (gid < 768) ? gid : gid - 768;
    int h = g >> 7, k = g & 127;
    const float* a = (gid < 768) ? al3 : ar3;
    float s = 0.f;
#pragma unroll
    for (int d = 0; d < 64; ++d) s += W3[(size_t)k * 384 + h * 64 + d] * a[h * 64 + d];
    if (gid < 768) al3c[g] = s; else ar3c[g] = s;
}

__global__ void k_prep_mb(const float* __restrict__ b3, float* __restrict__ mb) {
    int d = threadIdx.x;
    if (d >= 64) return;
    float s = 0.f;
#pragma unroll
    for (int h = 0; h < 6; ++h) s += b3[h * 64 + d];
    mb[d] = s * (1.f / 6.f);
}

// ---------------------------------------------------------------- CSR build
__global__ void k_hist2(const int* __restrict__ dst, int* __restrict__ cnt,
                        int* __restrict__ rank, int e) {
    int gid = blockIdx.x * blockDim.x + threadIdx.x;
    if (gid < e) rank[gid] = atomicAdd(&cnt[dst[gid]], 1);
}

__global__ void k_bsum(const int* __restrict__ deg, int* __restrict__ bsum, int n) {
    __shared__ int sm[256];
    int t = threadIdx.x;
    int i = blockIdx.x * 256 + t;
    sm[t] = (i < n) ? deg[i] : 0;
    __syncthreads();
#pragma unroll
    for (int off = 128; off > 0; off >>= 1) {
        if (t < off) sm[t] += sm[t + off];
        __syncthreads();
    }
    if (t == 0) bsum[blockIdx.x] = sm[0];
}

__global__ void k_bscan(const int* __restrict__ bsum, int* __restrict__ bpre, int nb) {
    __shared__ int sm[256];
    int t = threadIdx.x;
    int v = (t < nb) ? bsum[t] : 0;
    sm[t] = v;
    __syncthreads();
    for (int off = 1; off < 256; off <<= 1) {
        int u = (t >= off) ? sm[t - off] : 0;
        __syncthreads();
        sm[t] += u;
        __syncthreads();
    }
    if (t < nb) bpre[t] = sm[t] - v;
}

__global__ void k_offs(const int* __restrict__ deg, const int* __restrict__ bpre,
                       int* __restrict__ offs, int n, int e) {
    __shared__ int sm[256];
    int t = threadIdx.x;
    int i = blockIdx.x * 256 + t;
    int v = (i < n) ? deg[i] : 0;
    sm[t] = v;
    __syncthreads();
    for (int off = 1; off < 256; off <<= 1) {
        int u = (t >= off) ? sm[t - off] : 0;
        __syncthreads();
        sm[t] += u;
        __syncthreads();
    }
    if (i < n) offs[i] = bpre[blockIdx.x] + sm[t] - v;
    if (i == 0) offs[n] = e;
}

__global__ void k_fill2(const int* __restrict__ src, const int* __restrict__ dst,
                        const int* __restrict__ offs, const int* __restrict__ rank,
                        int2* __restrict__ csr2, int e) {
    int gid = blockIdx.x * blockDim.x + threadIdx.x;
    if (gid < e) {
        int d = dst[gid];
        int pos = offs[d] + rank[gid];
        csr2[pos] = make_int2(src[gid], d);
    }
}

// ---------------------------------------------------------------- edge weights (bf16)
__global__ void k_ew4(const int2* __restrict__ csr2, const float* __restrict__ el,
                      const float* __restrict__ er, unsigned short* __restrict__ aw, int e) {
    int gid = blockIdx.x * blockDim.x + threadIdx.x;
    if (gid >= e) return;
    int2 sd = csr2[gid];
    float4 l4 = *reinterpret_cast<const float4*>(el + (size_t)sd.x * 4);
    float4 r4 = *reinterpret_cast<const float4*>(er + (size_t)sd.y * 4);
    float w0 = __expf(leaky(l4.x + r4.x));
    float w1 = __expf(leaky(l4.y + r4.y));
    float w2 = __expf(leaky(l4.z + r4.z));
    float w3 = __expf(leaky(l4.w + r4.w));
    unsigned u0 = f2bf(w0) | (f2bf(w1) << 16);
    unsigned u1 = f2bf(w2) | (f2bf(w3) << 16);
    *reinterpret_cast<uint2*>(aw + (size_t)gid * 4) = make_uint2(u0, u1);
}

__global__ void k_ew6(const int2* __restrict__ csr2, const float* __restrict__ el,
                      const float* __restrict__ er, unsigned short* __restrict__ aw, int e) {
    int gid = blockIdx.x * blockDim.x + threadIdx.x;
    if (gid >= e) return;
    int2 sd = csr2[gid];
    const float2* lp = reinterpret_cast<const float2*>(el + (size_t)sd.x * 6);
    const float2* rp = reinterpret_cast<const float2*>(er + (size_t)sd.y * 6);
    float2 l0 = lp[0], l1 = lp[1], l2 = lp[2];
    float2 r0 = rp[0], r1 = rp[1], r2 = rp[2];
    unsigned w01 = f2bf(__expf(leaky(l0.x + r0.x))) | (f2bf(__expf(leaky(l0.y + r0.y))) << 16);
    unsigned w23 = f2bf(__expf(leaky(l1.x + r1.x))) | (f2bf(__expf(leaky(l1.y + r1.y))) << 16);
    unsigned w45 = f2bf(__expf(leaky(l2.x + r2.x))) | (f2bf(__expf(leaky(l2.y + r2.y))) << 16);
    unsigned char* wb = reinterpret_cast<unsigned char*>(aw) + (size_t)gid * 12;
    *reinterpret_cast<unsigned*>(wb + 0) = w01;
    *reinterpret_cast<unsigned*>(wb + 4) = w23;
    *reinterpret_cast<unsigned*>(wb + 8) = w45;
}

// ---------------------------------------------------------------- denominators
__global__ void k_denom4(const unsigned short* __restrict__ aw,
                         const int* __restrict__ offs, float* __restrict__ inv4, int n) {
    int gid = blockIdx.x * blockDim.x + threadIdx.x;
    if (gid >= n) return;
    int o0 = offs[gid], o1 = offs[gid + 1];
    float s0 = 0.f, s1 = 0.f, s2 = 0.f, s3 = 0.f;
    for (int p = o0; p < o1; ++p) {
        uint2 wu = *reinterpret_cast<const uint2*>(aw + (size_t)p * 4);
        s0 += blo(wu.x); s1 += bhi(wu.x);
        s2 += blo(wu.y); s3 += bhi(wu.y);
    }
    float4 r = (o1 > o0) ? make_float4(1.f / s0, 1.f / s1, 1.f / s2, 1.f / s3)
                         : make_float4(0.f, 0.f, 0.f, 0.f);
    *reinterpret_cast<float4*>(inv4 + (size_t)gid * 4) = r;
}

__global__ void k_denom6(const unsigned short* __restrict__ aw,
                         const int* __restrict__ offs, float* __restrict__ inv6, int n) {
    int gid = blockIdx.x * blockDim.x + threadIdx.x;
    if (gid >= n) return;
    int o0 = offs[gid], o1 = offs[gid + 1];
    float s[6] = {0.f, 0.f, 0.f, 0.f, 0.f, 0.f};
    const unsigned char* awb = reinterpret_cast<const unsigned char*>(aw);
    for (int p = o0; p < o1; ++p) {
        const unsigned char* wb = awb + (size_t)p * 12;
        unsigned w01 = *reinterpret_cast<const unsigned*>(wb + 0);
        unsigned w23 = *reinterpret_cast<const unsigned*>(wb + 4);
        unsigned w45 = *reinterpret_cast<const unsigned*>(wb + 8);
        s[0] += blo(w01); s[1] += bhi(w01);
        s[2] += blo(w23); s[3] += bhi(w23);
        s[4] += blo(w45); s[5] += bhi(w45);
    }
    bool has = o1 > o0;
    float* o = inv6 + (size_t)gid * 6;
#pragma unroll
    for (int h = 0; h < 6; ++h) o[h] = has ? 1.f / s[h] : 0.f;
}

// ---------------------------------------------------------------- MFMA GEMM (layers 1-2)
__global__ __launch_bounds__(256) void k_mgemm128(const unsigned short* __restrict__ A,
                                                  const unsigned short* __restrict__ BT,
                                                  unsigned short* __restrict__ C0,
                                                  int nrows) {
    __shared__ char Alds[64 * 256];
    __shared__ char Blds[64 * 256];
    const int t  = threadIdx.x;
    const int n0 = blockIdx.x * 64;
    const int w  = t >> 6;
    const int l  = t & 63;
    const int lr = l & 15;
    const int lk = l >> 4;

    {
        int col8 = (t & 15) * 8;
        int bc   = col8 * 2;
#pragma unroll
        for (int p = 0; p < 4; ++p) {
            int row = p * 16 + (t >> 4);
            int gr  = n0 + row;
            uint4 v = make_uint4(0, 0, 0, 0);
            if (gr < nrows) v = *reinterpret_cast<const uint4*>(A + (size_t)gr * 128 + col8);
            *reinterpret_cast<uint4*>(Alds + SW(row, bc)) = v;
        }
    }

    const int rbase = (w & 1) * 32;
    const int cbase = (w >> 1) * 32;

    for (int ct = 0; ct < 2; ++ct) {
        __syncthreads();
        {
            int col8 = (t & 15) * 8;
            int bc   = col8 * 2;
#pragma unroll
            for (int p = 0; p < 4; ++p) {
                int row = p * 16 + (t >> 4);
                uint4 v = *reinterpret_cast<const uint4*>(BT + (size_t)(ct * 64 + row) * 128 + col8);
                *reinterpret_cast<uint4*>(Blds + SW(row, bc)) = v;
            }
        }
        __syncthreads();

        f4 acc00 = {0.f, 0.f, 0.f, 0.f}, acc01 = {0.f, 0.f, 0.f, 0.f};
        f4 acc10 = {0.f, 0.f, 0.f, 0.f}, acc11 = {0.f, 0.f, 0.f, 0.f};
#pragma unroll
        for (int kk = 0; kk < 4; ++kk) {
            int bck = kk * 64 + lk * 16;
            bh8 a0 = *reinterpret_cast<const bh8*>(Alds + SW(rbase + lr, bck));
            bh8 a1 = *reinterpret_cast<const bh8*>(Alds + SW(rbase + 16 + lr, bck));
            bh8 b0 = *reinterpret_cast<const bh8*>(Blds + SW(cbase + lr, bck));
            bh8 b1 = *reinterpret_cast<const bh8*>(Blds + SW(cbase + 16 + lr, bck));
            acc00 = __builtin_amdgcn_mfma_f32_16x16x32_bf16(a0, b0, acc00, 0, 0, 0);
            acc01 = __builtin_amdgcn_mfma_f32_16x16x32_bf16(a0, b1, acc01, 0, 0, 0);
            acc10 = __builtin_amdgcn_mfma_f32_16x16x32_bf16(a1, b0, acc10, 0, 0, 0);
            acc11 = __builtin_amdgcn_mfma_f32_16x16x32_bf16(a1, b1, acc11, 0, 0, 0);
        }

        const f4* accs[4] = {&acc00, &acc01, &acc10, &acc11};
#pragma unroll
        for (int m = 0; m < 2; ++m) {
#pragma unroll
            for (int j = 0; j < 4; ++j) {
                int gr = n0 + rbase + m * 16 + lk * 4 + j;
                if (gr >= nrows) continue;
#pragma unroll
                for (int n = 0; n < 2; ++n) {
                    float v = (*accs[m * 2 + n])[j];
                    C0[(size_t)gr * 128 + ct * 64 + cbase + n * 16 + lr] = (unsigned short)f2bf(v);
                }
            }
        }
    }
}

// ---------------------------------------------------------------- el / er, layers 1-2
template <int H, int D>
__global__ void k_elr_bf(const unsigned short* __restrict__ feat,
                         const float* __restrict__ al, const float* __restrict__ ar,
                         float* __restrict__ el, float* __restrict__ er, int total) {
    int gid = blockIdx.x * blockDim.x + threadIdx.x;
    if (gid >= total) return;
    int n = gid / H, h = gid - n * H;
    const uint4* f = reinterpret_cast<const uint4*>(feat + (size_t)n * (H * D) + h * D);
    const float4* a = reinterpret_cast<const float4*>(al + h * D);
    const float4* r = reinterpret_cast<const float4*>(ar + h * D);
    float sl = 0.f, sr = 0.f;
#pragma unroll
    for (int j = 0; j < D / 8; ++j) {
        uint4 v = f[j];
        float4 a0 = a[2 * j], a1 = a[2 * j + 1];
        float4 r0 = r[2 * j], r1 = r[2 * j + 1];
        float x0 = blo(v.x), x1 = bhi(v.x), x2 = blo(v.y), x3 = bhi(v.y);
        float x4 = blo(v.z), x5 = bhi(v.z), x6 = blo(v.w), x7 = bhi(v.w);
        sl += x0 * a0.x + x1 * a0.y + x2 * a0.z + x3 * a0.w +
              x4 * a1.x + x5 * a1.y + x6 * a1.z + x7 * a1.w;
        sr += x0 * r0.x + x1 * r0.y + x2 * r0.z + x3 * r0.w +
              x4 * r1.x + x5 * r1.y + x6 * r1.z + x7 * r1.w;
    }
    el[gid] = sl;
    er[gid] = sr;
}

// ---------------------------------------------------------------- el / er, layer 3
__global__ void k_elr3(const unsigned short* __restrict__ h2b,
                       const float* __restrict__ al3c, const float* __restrict__ ar3c,
                       float* __restrict__ el, float* __restrict__ er, int total) {
    int gid = blockIdx.x * blockDim.x + threadIdx.x;
    if (gid >= total) return;
    int n = gid / 6, h = gid - n * 6;
    const uint4* f = reinterpret_cast<const uint4*>(h2b + (size_t)n * 128);
    const float4* a = reinterpret_cast<const float4*>(al3c + h * 128);
    const float4* r = reinterpret_cast<const float4*>(ar3c + h * 128);
    float sl = 0.f, sr = 0.f;
#pragma unroll
    for (int j = 0; j < 16; ++j) {
        uint4 v = f[j];
        float4 a0 = a[2 * j], a1 = a[2 * j + 1];
        float4 r0 = r[2 * j], r1 = r[2 * j + 1];
        float x0 = blo(v.x), x1 = bhi(v.x), x2 = blo(v.y), x3 = bhi(v.y);
        float x4 = blo(v.z), x5 = bhi(v.z), x6 = blo(v.w), x7 = bhi(v.w);
        sl += x0 * a0.x + x1 * a0.y + x2 * a0.z + x3 * a0.w +
              x4 * a1.x + x5 * a1.y + x6 * a1.z + x7 * a1.w;
        sr += x0 * r0.x + x1 * r0.y + x2 * r0.z + x3 * r0.w +
              x4 * r1.x + x5 * r1.y + x6 * r1.z + x7 * r1.w;
    }
    el[gid] = sl;
    er[gid] = sr;
}

// ---------------------------------------------------------------- aggregation, layers 1-2
template <bool HASRES, bool WRITEF32>
__global__ __launch_bounds__(256) void k_aggr128d(
    const unsigned short* __restrict__ feat, const int2* __restrict__ csr2,
    const int* __restrict__ offs, const unsigned short* __restrict__ aw,
    const float* __restrict__ inv4, const float* __restrict__ bias,
    const float* __restrict__ resf, unsigned short* __restrict__ outb,
    float* __restrict__ outf, int nnodes) {
    int node = blockIdx.x * 4 + (threadIdx.x >> 6);
    if (node >= nnodes) return;
    int l = threadIdx.x & 63;
    int half = l >> 5;
    int ll = l & 31;
    int h = ll >> 3;
    int o0 = offs[node], o1 = offs[node + 1];
    float acc0 = 0.f, acc1 = 0.f, acc2 = 0.f, acc3 = 0.f;
    int nt = (o1 - o0 + 1) >> 1;
#pragma unroll 2
    for (int t = 0; t < nt; ++t) {
        int ei = o0 + 2 * t + half;
        int pos = (ei < o1) ? ei : EDGES;      // dummy slot: w == 0
        uint2 wu = *reinterpret_cast<const uint2*>(aw + (size_t)pos * 4);
        unsigned uw = (h & 2) ? wu.y : wu.x;
        float w = (h & 1) ? bhi(uw) : blo(uw);
        int sidx = csr2[pos].x;
        uint2 u = *reinterpret_cast<const uint2*>(feat + (size_t)sidx * 128 + 4 * ll);
        acc0 = fmaf(w, blo(u.x), acc0);
        acc1 = fmaf(w, bhi(u.x), acc1);
        acc2 = fmaf(w, blo(u.y), acc2);
        acc3 = fmaf(w, bhi(u.y), acc3);
    }
    acc0 += __shfl_xor(acc0, 32);
    acc1 += __shfl_xor(acc1, 32);
    acc2 += __shfl_xor(acc2, 32);
    acc3 += __shfl_xor(acc3, 32);
    float inv = inv4[(size_t)node * 4 + h];
    int f = 4 * ll;
    float4 bi = *reinterpret_cast<const float4*>(bias + f);
    float r0 = acc0 * inv + bi.x;
    float r1 = acc1 * inv + bi.y;
    float r2 = acc2 * inv + bi.z;
    float r3 = acc3 * inv + bi.w;
    if (HASRES) {
        float4 rv = *reinterpret_cast<const float4*>(resf + (size_t)node * 128 + f);
        r0 += rv.x; r1 += rv.y; r2 += rv.z; r3 += rv.w;
    }
    r0 = (r0 > 0.f) ? r0 : (__expf(r0) - 1.f);
    r1 = (r1 > 0.f) ? r1 : (__expf(r1) - 1.f);
    r2 = (r2 > 0.f) ? r2 : (__expf(r2) - 1.f);
    r3 = (r3 > 0.f) ? r3 : (__expf(r3) - 1.f);
    if (half == 0) {
        unsigned u0 = f2bf(r0) | (f2bf(r1) << 16);
        unsigned u1 = f2bf(r2) | (f2bf(r3) << 16);
        *reinterpret_cast<uint2*>(outb + (size_t)node * 128 + f) = make_uint2(u0, u1);
        if (WRITEF32)
            *reinterpret_cast<float4*>(outf + (size_t)node * 128 + f) =
                make_float4(r0, r1, r2, r3);
    }
}

// ---------------------------------------------------------------- fused layer-3: aggregate -> LDS z -> MFMA tail
// 512 threads, 32 nodes/block. Phase 1: wave w aggregates nodes w*4..w*4+3
// into zsm[ln][772] f32. Phase 2: 32x64 output tile, K=896 (6 z-tiles as
// hi/lo bf16 split on the fly + 1 h2 tile); B frags from L2-resident BT2.
#define ZSTRIDE 772
__global__ __launch_bounds__(512) void k_fuse3(
    const unsigned short* __restrict__ h2b, const int2* __restrict__ csr2,
    const int* __restrict__ offs, const unsigned short* __restrict__ aw6,
    const float* __restrict__ inv6, const unsigned short* __restrict__ BT2,
    const float* __restrict__ mb, float* __restrict__ out, int nnodes) {
    __shared__ float zsm[32][ZSTRIDE];   // 98.8 KB
    const int t = threadIdx.x;
    const int w = t >> 6;        // wave 0..7
    const int l = t & 63;
    const int half = l >> 5;
    const int ll = l & 31;
    const int n0 = blockIdx.x * 32;
    const unsigned char* awb = reinterpret_cast<const unsigned char*>(aw6);

    // ---- phase 1: aggregation into LDS
    for (int i = 0; i < 4; ++i) {
        int ln = w * 4 + i;
        int node = n0 + ln;
        if (node >= nnodes) break;   // wave-uniform
        float acc[6][4];
#pragma unroll
        for (int h = 0; h < 6; ++h)
#pragma unroll
            for (int j = 0; j < 4; ++j) acc[h][j] = 0.f;
        int o0 = offs[node], o1 = offs[node + 1];
        int nt = (o1 - o0 + 1) >> 1;
#pragma unroll 4
        for (int e = 0; e < nt; ++e) {
            int ei = o0 + 2 * e + half;
            int pos = (ei < o1) ? ei : EDGES;   // dummy slot: w == 0
            const unsigned char* wb = awb + (size_t)pos * 12;
            unsigned w01 = *reinterpret_cast<const unsigned*>(wb + 0);
            unsigned w23 = *reinterpret_cast<const unsigned*>(wb + 4);
            unsigned w45 = *reinterpret_cast<const unsigned*>(wb + 8);
            float wv[6] = {blo(w01), bhi(w01), blo(w23), bhi(w23), blo(w45), bhi(w45)};
            int sidx = csr2[pos].x;
            uint2 u = *reinterpret_cast<const uint2*>(h2b + (size_t)sidx * 128 + 4 * ll);
            float f0 = blo(u.x), f1 = bhi(u.x), f2 = blo(u.y), f3 = bhi(u.y);
#pragma unroll
            for (int h = 0; h < 6; ++h) {
                acc[h][0] = fmaf(wv[h], f0, acc[h][0]);
                acc[h][1] = fmaf(wv[h], f1, acc[h][1]);
                acc[h][2] = fmaf(wv[h], f2, acc[h][2]);
                acc[h][3] = fmaf(wv[h], f3, acc[h][3]);
            }
        }
#pragma unroll
        for (int h = 0; h < 6; ++h)
#pragma unroll
            for (int j = 0; j < 4; ++j) acc[h][j] += __shfl_xor(acc[h][j], 32);
        if (half == 0) {
            float2 i01 = *reinterpret_cast<const float2*>(inv6 + (size_t)node * 6 + 0);
            float2 i23 = *reinterpret_cast<const float2*>(inv6 + (size_t)node * 6 + 2);
            float2 i45 = *reinterpret_cast<const float2*>(inv6 + (size_t)node * 6 + 4);
            float iv[6] = {i01.x, i01.y, i23.x, i23.y, i45.x, i45.y};
#pragma unroll
            for (int h = 0; h < 6; ++h) {
                *reinterpret_cast<float4*>(&zsm[ln][h * 128 + 4 * ll]) =
                    make_float4(acc[h][0] * iv[h], acc[h][1] * iv[h],
                                acc[h][2] * iv[h], acc[h][3] * iv[h]);
            }
        }
    }
    __syncthreads();

    // ---- phase 2: 32x64 MFMA tile; wave w -> (row-frag w&1, col-frag w>>1)
    const int lr = l & 15;
    const int lk = l >> 4;
    const int rowfrag = (w & 1) * 16;
    const int colfrag = (w >> 1) * 16;
    const int colrow = colfrag + lr;     // BT2 row (output col)
    f4 acc = {0.f, 0.f, 0.f, 0.f};

    for (int kt = 0; kt < 6; ++kt) {
#pragma unroll
        for (int kk = 0; kk < 4; ++kk) {
            int koff = kt * 128 + kk * 32 + lk * 8;
            bh8 b = *reinterpret_cast<const bh8*>(BT2 + (size_t)colrow * 896 + koff);
            const float* zp = &zsm[rowfrag + lr][koff];
            bh8 ahi, alo;
#pragma unroll
            for (int j = 0; j < 8; ++j) {
                float zv = zp[j];
                unsigned hb = f2bf(zv);
                float rem = zv - __uint_as_float(hb << 16);
                ahi[j] = (short)hb;
                alo[j] = (short)f2bf(rem);
            }
            acc = __builtin_amdgcn_mfma_f32_16x16x32_bf16(ahi, b, acc, 0, 0, 0);
            acc = __builtin_amdgcn_mfma_f32_16x16x32_bf16(alo, b, acc, 0, 0, 0);
        }
    }
    {   // kt == 6: h2 residual tile (k 768..895)
        int gr = n0 + rowfrag + lr;
        bool valid = gr < nnodes;
#pragma unroll
        for (int kk = 0; kk < 4; ++kk) {
            int koff = 768 + kk * 32 + lk * 8;
            bh8 b = *reinterpret_cast<const bh8*>(BT2 + (size_t)colrow * 896 + koff);
            bh8 a = {0, 0, 0, 0, 0, 0, 0, 0};
            if (valid)
                a = *reinterpret_cast<const bh8*>(h2b + (size_t)gr * 128 + kk * 32 + lk * 8);
            acc = __builtin_amdgcn_mfma_f32_16x16x32_bf16(a, b, acc, 0, 0, 0);
        }
    }

    float mbv = mb[colfrag + lr];
#pragma unroll
    for (int j = 0; j < 4; ++j) {
        int gr = n0 + rowfrag + lk * 4 + j;
        if (gr < nnodes)
            out[(size_t)gr * 64 + colfrag + lr] = acc[j] * (1.f / 6.f) + mbv;
    }
}

// ---------------------------------------------------------------- launch
extern "C" void kernel_launch(void* const* d_in, const int* in_sizes, int n_in,
                              void* d_out, int out_size, void* d_ws, size_t ws_size,
                              hipStream_t stream) {
    const float* x     = (const float*)d_in[0];
    const int*   src   = (const int*)d_in[1];
    const int*   dst   = (const int*)d_in[2];
    const float* W1    = (const float*)d_in[3];
    const float* al1   = (const float*)d_in[4];
    const float* ar1   = (const float*)d_in[5];
    const float* b1    = (const float*)d_in[6];
    const float* W2    = (const float*)d_in[7];
    const float* al2   = (const float*)d_in[8];
    const float* ar2   = (const float*)d_in[9];
    const float* b2    = (const float*)d_in[10];
    const float* W3    = (const float*)d_in[11];
    const float* al3   = (const float*)d_in[12];
    const float* ar3   = (const float*)d_in[13];
    const float* b3    = (const float*)d_in[14];
    const float* Wres3 = (const float*)d_in[15];
    float* out = (float*)d_out;

    const int N = NODES, E = EDGES;
    const int NB = (N + 255) / 256;

    char*  ws = (char*)d_ws;
    size_t o  = 0;
    auto alloc = [&](size_t bytes) {
        size_t r = o;
        o += (bytes + 255) & ~(size_t)255;
        return r;
    };
    // persistent (~33 MB)
    int*            offs  = (int*)(ws + alloc((size_t)(N + 1) * 4));
    int*            cnt   = (int*)(ws + alloc((size_t)N * 4));
    int2*           csr2  = (int2*)(ws + alloc((size_t)(E + 1) * 8));
    float*          el    = (float*)(ws + alloc((size_t)N * 6 * 4));
    float*          er    = (float*)(ws + alloc((size_t)N * 6 * 4));
    unsigned short* aw    = (unsigned short*)(ws + alloc((size_t)(E + 1) * 6 * 2));
    float*          inv   = (float*)(ws + alloc((size_t)N * 6 * 4));     // inv4/inv6
    unsigned short* h2b   = (unsigned short*)(ws + alloc((size_t)N * 128 * 2));
    unsigned short* w1t   = (unsigned short*)(ws + alloc((size_t)128 * 128 * 2));
    unsigned short* w2t   = (unsigned short*)(ws + alloc((size_t)128 * 128 * 2));
    unsigned short* bt2   = (unsigned short*)(ws + alloc((size_t)64 * 896 * 2));
    float*          al3c  = (float*)(ws + alloc((size_t)768 * 4));
    float*          ar3c  = (float*)(ws + alloc((size_t)768 * 4));
    float*          mb    = (float*)(ws + alloc((size_t)64 * 4));
    int*            bsum  = (int*)(ws + alloc((size_t)256 * 4));
    int*            bpre  = (int*)(ws + alloc((size_t)256 * 4));
    // union region: L1/2 transients + rank (disjoint lifetimes; zf deleted)
    char* U = ws + alloc((size_t)70 * 1024 * 1024);
    unsigned short* xb    = (unsigned short*)(U);                        // 12.8M
    unsigned short* featb = (unsigned short*)(U + (size_t)N * 128 * 2);  // 12.8M
    unsigned short* h1b   = (unsigned short*)(U + (size_t)N * 256 * 2);  // 12.8M
    float*          h1f   = (float*)(U + (size_t)N * 384 * 2);           // 25.6M (ends 64M)
    int*            rank  = (int*)(U + (size_t)64 * 1024 * 1024);        // 3.2M @64M

    const int gE = (E + 255) / 256;
    const int g4 = (N * 4 + 255) / 256;
    const int g6 = (N * 6 + 255) / 256;
    const int gN = (N + 255) / 256;
    const int gA = (N + 3) / 4;
    const int gG = (N + 63) / 64;
    const int gF = (N + 31) / 32;

    // ---- prep
    k_cast<<<(N * 128 / 4 + 255) / 256, 256, 0, stream>>>(x, xb, N * 128 / 4);
    k_prepw<<<(128 * 128 + 255) / 256, 256, 0, stream>>>(W1, w1t, 128);
    k_prepw<<<(128 * 128 + 255) / 256, 256, 0, stream>>>(W2, w2t, 128);
    k_prep_bt2<<<(64 * 896 + 255) / 256, 256, 0, stream>>>(W3, Wres3, bt2);
    k_prep_alr3<<<6, 256, 0, stream>>>(W3, al3, ar3, al3c, ar3c);
    k_prep_mb<<<1, 64, 0, stream>>>(b3, mb);

    // ---- dummy edge slot: csr2[E]={0,0}; aw zeroed at both layouts' index E
    hipMemsetAsync(csr2 + E, 0, 8, stream);
    hipMemsetAsync((char*)aw + (size_t)E * 8, 0, 8, stream);    // ew4 layout dummy
    hipMemsetAsync((char*)aw + (size_t)E * 12, 0, 12, stream);  // ew6 layout dummy

    // ---- CSR by dst: hist+rank (atomic), parallel scan, atomic-free fill
    hipMemsetAsync(cnt, 0, (size_t)N * 4, stream);
    k_hist2<<<gE, 256, 0, stream>>>(dst, cnt, rank, E);
    k_bsum<<<NB, 256, 0, stream>>>(cnt, bsum, N);
    k_bscan<<<1, 256, 0, stream>>>(bsum, bpre, NB);
    k_offs<<<NB, 256, 0, stream>>>(cnt, bpre, offs, N, E);
    k_fill2<<<gE, 256, 0, stream>>>(src, dst, offs, rank, csr2, E);

    // ---- layer 1: x -> h1
    k_mgemm128<<<gG, 256, 0, stream>>>(xb, w1t, featb, N);
    k_elr_bf<4, 32><<<g4, 256, 0, stream>>>(featb, al1, ar1, el, er, N * 4);
    k_ew4<<<gE, 256, 0, stream>>>(csr2, el, er, aw, E);
    k_denom4<<<gN, 256, 0, stream>>>(aw, offs, inv, N);
    k_aggr128d<false, true><<<gA, 256, 0, stream>>>(featb, csr2, offs, aw, inv, b1,
                                                    nullptr, h1b, h1f, N);

    // ---- layer 2: h1 -> h2
    k_mgemm128<<<gG, 256, 0, stream>>>(h1b, w2t, featb, N);
    k_elr_bf<4, 32><<<g4, 256, 0, stream>>>(featb, al2, ar2, el, er, N * 4);
    k_ew4<<<gE, 256, 0, stream>>>(csr2, el, er, aw, E);
    k_denom4<<<gN, 256, 0, stream>>>(aw, offs, inv, N);
    k_aggr128d<true, false><<<gA, 256, 0, stream>>>(featb, csr2, offs, aw, inv, b2,
                                                    h1f, h2b, nullptr, N);

    // ---- layer 3: weights -> fused aggregate+tail GEMM (z stays in LDS)
    k_elr3<<<g6, 256, 0, stream>>>(h2b, al3c, ar3c, el, er, N * 6);
    k_ew6<<<gE, 256, 0, stream>>>(csr2, el, er, aw, E);
    k_denom6<<<gN, 256, 0, stream>>>(aw, offs, inv, N);
    k_fuse3<<<gF, 512, 0, stream>>>(h2b, csr2, offs, aw, inv, bt2, mb, out, N);
}

// Round 14
// 409.242 us; speedup vs baseline: 1.0920x; 1.0920x over previous
//
#include <hip/hip_runtime.h>
#include <hip/hip_bf16.h>

// DistGAT: 3-layer GAT, N=50000 nodes, E=800000 edges.
// R14: R13's layer-3 fusion retried at the right granularity. R13 failed on
//      occupancy (98.8KB LDS -> 1 block/CU -> 19.7% occ -> 664 GB/s). R14:
//      k_fuse3b = 256 thr / 4 waves / 16 nodes, zsm[16][772] = 49.4KB ->
//      3 blocks/CU (12 waves), cross-block phase overlap. N = 3125*16 exactly.
//      Phase 1 = R13's verified aggregation loop; phase 2 = one 16x16 frag per
//      wave (colfrag w*16, rows 0-15, K=896, on-the-fly hi/lo bf16 split).
// Everything else identical to R12 (parallel scan, atomic-free fill, int2 CSR,
// precomputed bf16 edge weights + denominators, bf16 MFMA GEMMs).

#define NODES 50000
#define EDGES 800000
#define NEG 0.2f

typedef __attribute__((ext_vector_type(8))) short bh8;
typedef __attribute__((ext_vector_type(4))) float f4;

__device__ __forceinline__ float leaky(float e) { return e > 0.f ? e : NEG * e; }
__device__ __forceinline__ float blo(unsigned u) { return __uint_as_float(u << 16); }
__device__ __forceinline__ float bhi(unsigned u) { return __uint_as_float(u & 0xffff0000u); }
__device__ __forceinline__ unsigned f2bf(float f) {  // RNE, low 16 bits valid
    unsigned u = __float_as_uint(f);
    return (u + 0x7fffu + ((u >> 16) & 1u)) >> 16;
}

// swizzled byte offset in a [rows][128-bf16] LDS tile (row stride 256 B)
#define SW(row, bc) (((row) << 8) + ((bc) ^ (((row) & 7) << 4)))

// ---------------------------------------------------------------- prep
__global__ void k_cast(const float* __restrict__ in, unsigned short* __restrict__ outb, int n4) {
    int gid = blockIdx.x * blockDim.x + threadIdx.x;
    if (gid >= n4) return;
    float4 v = *reinterpret_cast<const float4*>(in + (size_t)gid * 4);
    unsigned u0 = f2bf(v.x) | (f2bf(v.y) << 16);
    unsigned u1 = f2bf(v.z) | (f2bf(v.w) << 16);
    *reinterpret_cast<uint2*>(outb + (size_t)gid * 4) = make_uint2(u0, u1);
}

__global__ void k_prepw(const float* __restrict__ W, unsigned short* __restrict__ WT, int F) {
    int gid = blockIdx.x * blockDim.x + threadIdx.x;
    if (gid >= 128 * F) return;
    int k = gid / F, f = gid - k * F;
    WT[(size_t)f * 128 + k] = (unsigned short)f2bf(W[gid]);
}

__global__ void k_prep_bt2(const float* __restrict__ W3, const float* __restrict__ Wres3,
                           unsigned short* __restrict__ BT2) {
    int gid = blockIdx.x * blockDim.x + threadIdx.x;
    if (gid >= 64 * 896) return;
    int d = gid / 896, k = gid - d * 896;
    float v;
    if (k < 768) {
        v = W3[(size_t)(k & 127) * 384 + (k >> 7) * 64 + d];
    } else {
        int kr = k - 768;
        v = 0.f;
#pragma unroll
        for (int h = 0; h < 6; ++h) v += Wres3[(size_t)kr * 384 + h * 64 + d];
    }
    BT2[(size_t)d * 896 + k] = (unsigned short)f2bf(v);
}

__global__ void k_prep_alr3(const float* __restrict__ W3, const float* __restrict__ al3,
                            const float* __restrict__ ar3, float* __restrict__ al3c,
                            float* __restrict__ ar3c) {
    int gid = blockIdx.x * blockDim.x + threadIdx.x;
    if (gid >= 1536) return;
    int g = (gid < 768) ? gid : gid - 768;
    int h = g >> 7, k = g & 127;
    const float* a = (gid < 768) ? al3 : ar3;
    float s = 0.f;
#pragma unroll
    for (int d = 0; d < 64; ++d) s += W3[(size_t)k * 384 + h * 64 + d] * a[h * 64 + d];
    if (gid < 768) al3c[g] = s; else ar3c[g] = s;
}

__global__ void k_prep_mb(const float* __restrict__ b3, float* __restrict__ mb) {
    int d = threadIdx.x;
    if (d >= 64) return;
    float s = 0.f;
#pragma unroll
    for (int h = 0; h < 6; ++h) s += b3[h * 64 + d];
    mb[d] = s * (1.f / 6.f);
}

// ---------------------------------------------------------------- CSR build
__global__ void k_hist2(const int* __restrict__ dst, int* __restrict__ cnt,
                        int* __restrict__ rank, int e) {
    int gid = blockIdx.x * blockDim.x + threadIdx.x;
    if (gid < e) rank[gid] = atomicAdd(&cnt[dst[gid]], 1);
}

__global__ void k_bsum(const int* __restrict__ deg, int* __restrict__ bsum, int n) {
    __shared__ int sm[256];
    int t = threadIdx.x;
    int i = blockIdx.x * 256 + t;
    sm[t] = (i < n) ? deg[i] : 0;
    __syncthreads();
#pragma unroll
    for (int off = 128; off > 0; off >>= 1) {
        if (t < off) sm[t] += sm[t + off];
        __syncthreads();
    }
    if (t == 0) bsum[blockIdx.x] = sm[0];
}

__global__ void k_bscan(const int* __restrict__ bsum, int* __restrict__ bpre, int nb) {
    __shared__ int sm[256];
    int t = threadIdx.x;
    int v = (t < nb) ? bsum[t] : 0;
    sm[t] = v;
    __syncthreads();
    for (int off = 1; off < 256; off <<= 1) {
        int u = (t >= off) ? sm[t - off] : 0;
        __syncthreads();
        sm[t] += u;
        __syncthreads();
    }
    if (t < nb) bpre[t] = sm[t] - v;
}

__global__ void k_offs(const int* __restrict__ deg, const int* __restrict__ bpre,
                       int* __restrict__ offs, int n, int e) {
    __shared__ int sm[256];
    int t = threadIdx.x;
    int i = blockIdx.x * 256 + t;
    int v = (i < n) ? deg[i] : 0;
    sm[t] = v;
    __syncthreads();
    for (int off = 1; off < 256; off <<= 1) {
        int u = (t >= off) ? sm[t - off] : 0;
        __syncthreads();
        sm[t] += u;
        __syncthreads();
    }
    if (i < n) offs[i] = bpre[blockIdx.x] + sm[t] - v;
    if (i == 0) offs[n] = e;
}

__global__ void k_fill2(const int* __restrict__ src, const int* __restrict__ dst,
                        const int* __restrict__ offs, const int* __restrict__ rank,
                        int2* __restrict__ csr2, int e) {
    int gid = blockIdx.x * blockDim.x + threadIdx.x;
    if (gid < e) {
        int d = dst[gid];
        int pos = offs[d] + rank[gid];
        csr2[pos] = make_int2(src[gid], d);
    }
}

// ---------------------------------------------------------------- edge weights (bf16)
__global__ void k_ew4(const int2* __restrict__ csr2, const float* __restrict__ el,
                      const float* __restrict__ er, unsigned short* __restrict__ aw, int e) {
    int gid = blockIdx.x * blockDim.x + threadIdx.x;
    if (gid >= e) return;
    int2 sd = csr2[gid];
    float4 l4 = *reinterpret_cast<const float4*>(el + (size_t)sd.x * 4);
    float4 r4 = *reinterpret_cast<const float4*>(er + (size_t)sd.y * 4);
    float w0 = __expf(leaky(l4.x + r4.x));
    float w1 = __expf(leaky(l4.y + r4.y));
    float w2 = __expf(leaky(l4.z + r4.z));
    float w3 = __expf(leaky(l4.w + r4.w));
    unsigned u0 = f2bf(w0) | (f2bf(w1) << 16);
    unsigned u1 = f2bf(w2) | (f2bf(w3) << 16);
    *reinterpret_cast<uint2*>(aw + (size_t)gid * 4) = make_uint2(u0, u1);
}

__global__ void k_ew6(const int2* __restrict__ csr2, const float* __restrict__ el,
                      const float* __restrict__ er, unsigned short* __restrict__ aw, int e) {
    int gid = blockIdx.x * blockDim.x + threadIdx.x;
    if (gid >= e) return;
    int2 sd = csr2[gid];
    const float2* lp = reinterpret_cast<const float2*>(el + (size_t)sd.x * 6);
    const float2* rp = reinterpret_cast<const float2*>(er + (size_t)sd.y * 6);
    float2 l0 = lp[0], l1 = lp[1], l2 = lp[2];
    float2 r0 = rp[0], r1 = rp[1], r2 = rp[2];
    unsigned w01 = f2bf(__expf(leaky(l0.x + r0.x))) | (f2bf(__expf(leaky(l0.y + r0.y))) << 16);
    unsigned w23 = f2bf(__expf(leaky(l1.x + r1.x))) | (f2bf(__expf(leaky(l1.y + r1.y))) << 16);
    unsigned w45 = f2bf(__expf(leaky(l2.x + r2.x))) | (f2bf(__expf(leaky(l2.y + r2.y))) << 16);
    unsigned char* wb = reinterpret_cast<unsigned char*>(aw) + (size_t)gid * 12;
    *reinterpret_cast<unsigned*>(wb + 0) = w01;
    *reinterpret_cast<unsigned*>(wb + 4) = w23;
    *reinterpret_cast<unsigned*>(wb + 8) = w45;
}

// ---------------------------------------------------------------- denominators
__global__ void k_denom4(const unsigned short* __restrict__ aw,
                         const int* __restrict__ offs, float* __restrict__ inv4, int n) {
    int gid = blockIdx.x * blockDim.x + threadIdx.x;
    if (gid >= n) return;
    int o0 = offs[gid], o1 = offs[gid + 1];
    float s0 = 0.f, s1 = 0.f, s2 = 0.f, s3 = 0.f;
    for (int p = o0; p < o1; ++p) {
        uint2 wu = *reinterpret_cast<const uint2*>(aw + (size_t)p * 4);
        s0 += blo(wu.x); s1 += bhi(wu.x);
        s2 += blo(wu.y); s3 += bhi(wu.y);
    }
    float4 r = (o1 > o0) ? make_float4(1.f / s0, 1.f / s1, 1.f / s2, 1.f / s3)
                         : make_float4(0.f, 0.f, 0.f, 0.f);
    *reinterpret_cast<float4*>(inv4 + (size_t)gid * 4) = r;
}

__global__ void k_denom6(const unsigned short* __restrict__ aw,
                         const int* __restrict__ offs, float* __restrict__ inv6, int n) {
    int gid = blockIdx.x * blockDim.x + threadIdx.x;
    if (gid >= n) return;
    int o0 = offs[gid], o1 = offs[gid + 1];
    float s[6] = {0.f, 0.f, 0.f, 0.f, 0.f, 0.f};
    const unsigned char* awb = reinterpret_cast<const unsigned char*>(aw);
    for (int p = o0; p < o1; ++p) {
        const unsigned char* wb = awb + (size_t)p * 12;
        unsigned w01 = *reinterpret_cast<const unsigned*>(wb + 0);
        unsigned w23 = *reinterpret_cast<const unsigned*>(wb + 4);
        unsigned w45 = *reinterpret_cast<const unsigned*>(wb + 8);
        s[0] += blo(w01); s[1] += bhi(w01);
        s[2] += blo(w23); s[3] += bhi(w23);
        s[4] += blo(w45); s[5] += bhi(w45);
    }
    bool has = o1 > o0;
    float* o = inv6 + (size_t)gid * 6;
#pragma unroll
    for (int h = 0; h < 6; ++h) o[h] = has ? 1.f / s[h] : 0.f;
}

// ---------------------------------------------------------------- MFMA GEMM (layers 1-2)
__global__ __launch_bounds__(256) void k_mgemm128(const unsigned short* __restrict__ A,
                                                  const unsigned short* __restrict__ BT,
                                                  unsigned short* __restrict__ C0,
                                                  int nrows) {
    __shared__ char Alds[64 * 256];
    __shared__ char Blds[64 * 256];
    const int t  = threadIdx.x;
    const int n0 = blockIdx.x * 64;
    const int w  = t >> 6;
    const int l  = t & 63;
    const int lr = l & 15;
    const int lk = l >> 4;

    {
        int col8 = (t & 15) * 8;
        int bc   = col8 * 2;
#pragma unroll
        for (int p = 0; p < 4; ++p) {
            int row = p * 16 + (t >> 4);
            int gr  = n0 + row;
            uint4 v = make_uint4(0, 0, 0, 0);
            if (gr < nrows) v = *reinterpret_cast<const uint4*>(A + (size_t)gr * 128 + col8);
            *reinterpret_cast<uint4*>(Alds + SW(row, bc)) = v;
        }
    }

    const int rbase = (w & 1) * 32;
    const int cbase = (w >> 1) * 32;

    for (int ct = 0; ct < 2; ++ct) {
        __syncthreads();
        {
            int col8 = (t & 15) * 8;
            int bc   = col8 * 2;
#pragma unroll
            for (int p = 0; p < 4; ++p) {
                int row = p * 16 + (t >> 4);
                uint4 v = *reinterpret_cast<const uint4*>(BT + (size_t)(ct * 64 + row) * 128 + col8);
                *reinterpret_cast<uint4*>(Blds + SW(row, bc)) = v;
            }
        }
        __syncthreads();

        f4 acc00 = {0.f, 0.f, 0.f, 0.f}, acc01 = {0.f, 0.f, 0.f, 0.f};
        f4 acc10 = {0.f, 0.f, 0.f, 0.f}, acc11 = {0.f, 0.f, 0.f, 0.f};
#pragma unroll
        for (int kk = 0; kk < 4; ++kk) {
            int bck = kk * 64 + lk * 16;
            bh8 a0 = *reinterpret_cast<const bh8*>(Alds + SW(rbase + lr, bck));
            bh8 a1 = *reinterpret_cast<const bh8*>(Alds + SW(rbase + 16 + lr, bck));
            bh8 b0 = *reinterpret_cast<const bh8*>(Blds + SW(cbase + lr, bck));
            bh8 b1 = *reinterpret_cast<const bh8*>(Blds + SW(cbase + 16 + lr, bck));
            acc00 = __builtin_amdgcn_mfma_f32_16x16x32_bf16(a0, b0, acc00, 0, 0, 0);
            acc01 = __builtin_amdgcn_mfma_f32_16x16x32_bf16(a0, b1, acc01, 0, 0, 0);
            acc10 = __builtin_amdgcn_mfma_f32_16x16x32_bf16(a1, b0, acc10, 0, 0, 0);
            acc11 = __builtin_amdgcn_mfma_f32_16x16x32_bf16(a1, b1, acc11, 0, 0, 0);
        }

        const f4* accs[4] = {&acc00, &acc01, &acc10, &acc11};
#pragma unroll
        for (int m = 0; m < 2; ++m) {
#pragma unroll
            for (int j = 0; j < 4; ++j) {
                int gr = n0 + rbase + m * 16 + lk * 4 + j;
                if (gr >= nrows) continue;
#pragma unroll
                for (int n = 0; n < 2; ++n) {
                    float v = (*accs[m * 2 + n])[j];
                    C0[(size_t)gr * 128 + ct * 64 + cbase + n * 16 + lr] = (unsigned short)f2bf(v);
                }
            }
        }
    }
}

// ---------------------------------------------------------------- el / er, layers 1-2
template <int H, int D>
__global__ void k_elr_bf(const unsigned short* __restrict__ feat,
                         const float* __restrict__ al, const float* __restrict__ ar,
                         float* __restrict__ el, float* __restrict__ er, int total) {
    int gid = blockIdx.x * blockDim.x + threadIdx.x;
    if (gid >= total) return;
    int n = gid / H, h = gid - n * H;
    const uint4* f = reinterpret_cast<const uint4*>(feat + (size_t)n * (H * D) + h * D);
    const float4* a = reinterpret_cast<const float4*>(al + h * D);
    const float4* r = reinterpret_cast<const float4*>(ar + h * D);
    float sl = 0.f, sr = 0.f;
#pragma unroll
    for (int j = 0; j < D / 8; ++j) {
        uint4 v = f[j];
        float4 a0 = a[2 * j], a1 = a[2 * j + 1];
        float4 r0 = r[2 * j], r1 = r[2 * j + 1];
        float x0 = blo(v.x), x1 = bhi(v.x), x2 = blo(v.y), x3 = bhi(v.y);
        float x4 = blo(v.z), x5 = bhi(v.z), x6 = blo(v.w), x7 = bhi(v.w);
        sl += x0 * a0.x + x1 * a0.y + x2 * a0.z + x3 * a0.w +
              x4 * a1.x + x5 * a1.y + x6 * a1.z + x7 * a1.w;
        sr += x0 * r0.x + x1 * r0.y + x2 * r0.z + x3 * r0.w +
              x4 * r1.x + x5 * r1.y + x6 * r1.z + x7 * r1.w;
    }
    el[gid] = sl;
    er[gid] = sr;
}

// ---------------------------------------------------------------- el / er, layer 3
__global__ void k_elr3(const unsigned short* __restrict__ h2b,
                       const float* __restrict__ al3c, const float* __restrict__ ar3c,
                       float* __restrict__ el, float* __restrict__ er, int total) {
    int gid = blockIdx.x * blockDim.x + threadIdx.x;
    if (gid >= total) return;
    int n = gid / 6, h = gid - n * 6;
    const uint4* f = reinterpret_cast<const uint4*>(h2b + (size_t)n * 128);
    const float4* a = reinterpret_cast<const float4*>(al3c + h * 128);
    const float4* r = reinterpret_cast<const float4*>(ar3c + h * 128);
    float sl = 0.f, sr = 0.f;
#pragma unroll
    for (int j = 0; j < 16; ++j) {
        uint4 v = f[j];
        float4 a0 = a[2 * j], a1 = a[2 * j + 1];
        float4 r0 = r[2 * j], r1 = r[2 * j + 1];
        float x0 = blo(v.x), x1 = bhi(v.x), x2 = blo(v.y), x3 = bhi(v.y);
        float x4 = blo(v.z), x5 = bhi(v.z), x6 = blo(v.w), x7 = bhi(v.w);
        sl += x0 * a0.x + x1 * a0.y + x2 * a0.z + x3 * a0.w +
              x4 * a1.x + x5 * a1.y + x6 * a1.z + x7 * a1.w;
        sr += x0 * r0.x + x1 * r0.y + x2 * r0.z + x3 * r0.w +
              x4 * r1.x + x5 * r1.y + x6 * r1.z + x7 * r1.w;
    }
    el[gid] = sl;
    er[gid] = sr;
}

// ---------------------------------------------------------------- aggregation, layers 1-2
template <bool HASRES, bool WRITEF32>
__global__ __launch_bounds__(256) void k_aggr128d(
    const unsigned short* __restrict__ feat, const int2* __restrict__ csr2,
    const int* __restrict__ offs, const unsigned short* __restrict__ aw,
    const float* __restrict__ inv4, const float* __restrict__ bias,
    const float* __restrict__ resf, unsigned short* __restrict__ outb,
    float* __restrict__ outf, int nnodes) {
    int node = blockIdx.x * 4 + (threadIdx.x >> 6);
    if (node >= nnodes) return;
    int l = threadIdx.x & 63;
    int half = l >> 5;
    int ll = l & 31;
    int h = ll >> 3;
    int o0 = offs[node], o1 = offs[node + 1];
    float acc0 = 0.f, acc1 = 0.f, acc2 = 0.f, acc3 = 0.f;
    int nt = (o1 - o0 + 1) >> 1;
#pragma unroll 2
    for (int t = 0; t < nt; ++t) {
        int ei = o0 + 2 * t + half;
        int pos = (ei < o1) ? ei : EDGES;      // dummy slot: w == 0
        uint2 wu = *reinterpret_cast<const uint2*>(aw + (size_t)pos * 4);
        unsigned uw = (h & 2) ? wu.y : wu.x;
        float w = (h & 1) ? bhi(uw) : blo(uw);
        int sidx = csr2[pos].x;
        uint2 u = *reinterpret_cast<const uint2*>(feat + (size_t)sidx * 128 + 4 * ll);
        acc0 = fmaf(w, blo(u.x), acc0);
        acc1 = fmaf(w, bhi(u.x), acc1);
        acc2 = fmaf(w, blo(u.y), acc2);
        acc3 = fmaf(w, bhi(u.y), acc3);
    }
    acc0 += __shfl_xor(acc0, 32);
    acc1 += __shfl_xor(acc1, 32);
    acc2 += __shfl_xor(acc2, 32);
    acc3 += __shfl_xor(acc3, 32);
    float inv = inv4[(size_t)node * 4 + h];
    int f = 4 * ll;
    float4 bi = *reinterpret_cast<const float4*>(bias + f);
    float r0 = acc0 * inv + bi.x;
    float r1 = acc1 * inv + bi.y;
    float r2 = acc2 * inv + bi.z;
    float r3 = acc3 * inv + bi.w;
    if (HASRES) {
        float4 rv = *reinterpret_cast<const float4*>(resf + (size_t)node * 128 + f);
        r0 += rv.x; r1 += rv.y; r2 += rv.z; r3 += rv.w;
    }
    r0 = (r0 > 0.f) ? r0 : (__expf(r0) - 1.f);
    r1 = (r1 > 0.f) ? r1 : (__expf(r1) - 1.f);
    r2 = (r2 > 0.f) ? r2 : (__expf(r2) - 1.f);
    r3 = (r3 > 0.f) ? r3 : (__expf(r3) - 1.f);
    if (half == 0) {
        unsigned u0 = f2bf(r0) | (f2bf(r1) << 16);
        unsigned u1 = f2bf(r2) | (f2bf(r3) << 16);
        *reinterpret_cast<uint2*>(outb + (size_t)node * 128 + f) = make_uint2(u0, u1);
        if (WRITEF32)
            *reinterpret_cast<float4*>(outf + (size_t)node * 128 + f) =
                make_float4(r0, r1, r2, r3);
    }
}

// ---------------------------------------------------------------- fused layer-3 (16-node blocks)
// 256 threads / 4 waves / 16 nodes. Phase 1: wave w aggregates nodes w*4..+3
// into zsm[ln][772] f32 (49.4KB -> 3 blocks/CU). Phase 2: 16x64 output tile,
// wave w owns cols w*16..+15; K=896 (6 z-tiles hi/lo-split from LDS + 1 h2).
#define ZSTRIDE 772
__global__ __launch_bounds__(256) void k_fuse3b(
    const unsigned short* __restrict__ h2b, const int2* __restrict__ csr2,
    const int* __restrict__ offs, const unsigned short* __restrict__ aw6,
    const float* __restrict__ inv6, const unsigned short* __restrict__ BT2,
    const float* __restrict__ mb, float* __restrict__ out, int nnodes) {
    __shared__ float zsm[16][ZSTRIDE];   // 49.4 KB
    const int t = threadIdx.x;
    const int w = t >> 6;        // wave 0..3
    const int l = t & 63;
    const int half = l >> 5;
    const int ll = l & 31;
    const int n0 = blockIdx.x * 16;
    const unsigned char* awb = reinterpret_cast<const unsigned char*>(aw6);

    // ---- phase 1: aggregation into LDS (numerics identical to R12 aggrZ3)
    for (int i = 0; i < 4; ++i) {
        int ln = w * 4 + i;
        int node = n0 + ln;
        if (node >= nnodes) break;   // wave-uniform
        float acc[6][4];
#pragma unroll
        for (int h = 0; h < 6; ++h)
#pragma unroll
            for (int j = 0; j < 4; ++j) acc[h][j] = 0.f;
        int o0 = offs[node], o1 = offs[node + 1];
        int nt = (o1 - o0 + 1) >> 1;
#pragma unroll 4
        for (int e = 0; e < nt; ++e) {
            int ei = o0 + 2 * e + half;
            int pos = (ei < o1) ? ei : EDGES;   // dummy slot: w == 0
            const unsigned char* wb = awb + (size_t)pos * 12;
            unsigned w01 = *reinterpret_cast<const unsigned*>(wb + 0);
            unsigned w23 = *reinterpret_cast<const unsigned*>(wb + 4);
            unsigned w45 = *reinterpret_cast<const unsigned*>(wb + 8);
            float wv[6] = {blo(w01), bhi(w01), blo(w23), bhi(w23), blo(w45), bhi(w45)};
            int sidx = csr2[pos].x;
            uint2 u = *reinterpret_cast<const uint2*>(h2b + (size_t)sidx * 128 + 4 * ll);
            float f0 = blo(u.x), f1 = bhi(u.x), f2 = blo(u.y), f3 = bhi(u.y);
#pragma unroll
            for (int h = 0; h < 6; ++h) {
                acc[h][0] = fmaf(wv[h], f0, acc[h][0]);
                acc[h][1] = fmaf(wv[h], f1, acc[h][1]);
                acc[h][2] = fmaf(wv[h], f2, acc[h][2]);
                acc[h][3] = fmaf(wv[h], f3, acc[h][3]);
            }
        }
#pragma unroll
        for (int h = 0; h < 6; ++h)
#pragma unroll
            for (int j = 0; j < 4; ++j) acc[h][j] += __shfl_xor(acc[h][j], 32);
        if (half == 0) {
            float2 i01 = *reinterpret_cast<const float2*>(inv6 + (size_t)node * 6 + 0);
            float2 i23 = *reinterpret_cast<const float2*>(inv6 + (size_t)node * 6 + 2);
            float2 i45 = *reinterpret_cast<const float2*>(inv6 + (size_t)node * 6 + 4);
            float iv[6] = {i01.x, i01.y, i23.x, i23.y, i45.x, i45.y};
#pragma unroll
            for (int h = 0; h < 6; ++h) {
                *reinterpret_cast<float4*>(&zsm[ln][h * 128 + 4 * ll]) =
                    make_float4(acc[h][0] * iv[h], acc[h][1] * iv[h],
                                acc[h][2] * iv[h], acc[h][3] * iv[h]);
            }
        }
    }
    __syncthreads();

    // ---- phase 2: 16x64 tile; wave w -> cols w*16..+15, rows 0..15
    const int lr = l & 15;
    const int lk = l >> 4;
    const int colrow = w * 16 + lr;      // BT2 row (output col)
    f4 acc = {0.f, 0.f, 0.f, 0.f};

    for (int kt = 0; kt < 6; ++kt) {
#pragma unroll
        for (int kk = 0; kk < 4; ++kk) {
            int koff = kt * 128 + kk * 32 + lk * 8;
            bh8 b = *reinterpret_cast<const bh8*>(BT2 + (size_t)colrow * 896 + koff);
            const float* zp = &zsm[lr][koff];
            bh8 ahi, alo;
#pragma unroll
            for (int j = 0; j < 8; ++j) {
                float zv = zp[j];
                unsigned hb = f2bf(zv);
                float rem = zv - __uint_as_float(hb << 16);
                ahi[j] = (short)hb;
                alo[j] = (short)f2bf(rem);
            }
            acc = __builtin_amdgcn_mfma_f32_16x16x32_bf16(ahi, b, acc, 0, 0, 0);
            acc = __builtin_amdgcn_mfma_f32_16x16x32_bf16(alo, b, acc, 0, 0, 0);
        }
    }
    {   // kt == 6: h2 residual tile (k 768..895)
        int gr = n0 + lr;
        bool valid = gr < nnodes;
#pragma unroll
        for (int kk = 0; kk < 4; ++kk) {
            int koff = 768 + kk * 32 + lk * 8;
            bh8 b = *reinterpret_cast<const bh8*>(BT2 + (size_t)colrow * 896 + koff);
            bh8 a = {0, 0, 0, 0, 0, 0, 0, 0};
            if (valid)
                a = *reinterpret_cast<const bh8*>(h2b + (size_t)gr * 128 + kk * 32 + lk * 8);
            acc = __builtin_amdgcn_mfma_f32_16x16x32_bf16(a, b, acc, 0, 0, 0);
        }
    }

    float mbv = mb[colrow & 63];
#pragma unroll
    for (int j = 0; j < 4; ++j) {
        int gr = n0 + lk * 4 + j;
        if (gr < nnodes)
            out[(size_t)gr * 64 + colrow] = acc[j] * (1.f / 6.f) + mbv;
    }
}

// ---------------------------------------------------------------- launch
extern "C" void kernel_launch(void* const* d_in, const int* in_sizes, int n_in,
                              void* d_out, int out_size, void* d_ws, size_t ws_size,
                              hipStream_t stream) {
    const float* x     = (const float*)d_in[0];
    const int*   src   = (const int*)d_in[1];
    const int*   dst   = (const int*)d_in[2];
    const float* W1    = (const float*)d_in[3];
    const float* al1   = (const float*)d_in[4];
    const float* ar1   = (const float*)d_in[5];
    const float* b1    = (const float*)d_in[6];
    const float* W2    = (const float*)d_in[7];
    const float* al2   = (const float*)d_in[8];
    const float* ar2   = (const float*)d_in[9];
    const float* b2    = (const float*)d_in[10];
    const float* W3    = (const float*)d_in[11];
    const float* al3   = (const float*)d_in[12];
    const float* ar3   = (const float*)d_in[13];
    const float* b3    = (const float*)d_in[14];
    const float* Wres3 = (const float*)d_in[15];
    float* out = (float*)d_out;

    const int N = NODES, E = EDGES;
    const int NB = (N + 255) / 256;

    char*  ws = (char*)d_ws;
    size_t o  = 0;
    auto alloc = [&](size_t bytes) {
        size_t r = o;
        o += (bytes + 255) & ~(size_t)255;
        return r;
    };
    // persistent (~33 MB)
    int*            offs  = (int*)(ws + alloc((size_t)(N + 1) * 4));
    int*            cnt   = (int*)(ws + alloc((size_t)N * 4));
    int2*           csr2  = (int2*)(ws + alloc((size_t)(E + 1) * 8));
    float*          el    = (float*)(ws + alloc((size_t)N * 6 * 4));
    float*          er    = (float*)(ws + alloc((size_t)N * 6 * 4));
    unsigned short* aw    = (unsigned short*)(ws + alloc((size_t)(E + 1) * 6 * 2));
    float*          inv   = (float*)(ws + alloc((size_t)N * 6 * 4));     // inv4/inv6
    unsigned short* h2b   = (unsigned short*)(ws + alloc((size_t)N * 128 * 2));
    unsigned short* w1t   = (unsigned short*)(ws + alloc((size_t)128 * 128 * 2));
    unsigned short* w2t   = (unsigned short*)(ws + alloc((size_t)128 * 128 * 2));
    unsigned short* bt2   = (unsigned short*)(ws + alloc((size_t)64 * 896 * 2));
    float*          al3c  = (float*)(ws + alloc((size_t)768 * 4));
    float*          ar3c  = (float*)(ws + alloc((size_t)768 * 4));
    float*          mb    = (float*)(ws + alloc((size_t)64 * 4));
    int*            bsum  = (int*)(ws + alloc((size_t)256 * 4));
    int*            bpre  = (int*)(ws + alloc((size_t)256 * 4));
    // union region: L1/2 transients + rank (disjoint lifetimes)
    char* U = ws + alloc((size_t)70 * 1024 * 1024);
    unsigned short* xb    = (unsigned short*)(U);                        // 12.8M
    unsigned short* featb = (unsigned short*)(U + (size_t)N * 128 * 2);  // 12.8M
    unsigned short* h1b   = (unsigned short*)(U + (size_t)N * 256 * 2);  // 12.8M
    float*          h1f   = (float*)(U + (size_t)N * 384 * 2);           // 25.6M (ends 64M)
    int*            rank  = (int*)(U + (size_t)64 * 1024 * 1024);        // 3.2M @64M

    const int gE = (E + 255) / 256;
    const int g4 = (N * 4 + 255) / 256;
    const int g6 = (N * 6 + 255) / 256;
    const int gN = (N + 255) / 256;
    const int gA = (N + 3) / 4;
    const int gG = (N + 63) / 64;
    const int gF = (N + 15) / 16;   // 3125, exact

    // ---- prep
    k_cast<<<(N * 128 / 4 + 255) / 256, 256, 0, stream>>>(x, xb, N * 128 / 4);
    k_prepw<<<(128 * 128 + 255) / 256, 256, 0, stream>>>(W1, w1t, 128);
    k_prepw<<<(128 * 128 + 255) / 256, 256, 0, stream>>>(W2, w2t, 128);
    k_prep_bt2<<<(64 * 896 + 255) / 256, 256, 0, stream>>>(W3, Wres3, bt2);
    k_prep_alr3<<<6, 256, 0, stream>>>(W3, al3, ar3, al3c, ar3c);
    k_prep_mb<<<1, 64, 0, stream>>>(b3, mb);

    // ---- dummy edge slot: csr2[E]={0,0}; aw zeroed at both layouts' index E
    hipMemsetAsync(csr2 + E, 0, 8, stream);
    hipMemsetAsync((char*)aw + (size_t)E * 8, 0, 8, stream);    // ew4 layout dummy
    hipMemsetAsync((char*)aw + (size_t)E * 12, 0, 12, stream);  // ew6 layout dummy

    // ---- CSR by dst: hist+rank (atomic), parallel scan, atomic-free fill
    hipMemsetAsync(cnt, 0, (size_t)N * 4, stream);
    k_hist2<<<gE, 256, 0, stream>>>(dst, cnt, rank, E);
    k_bsum<<<NB, 256, 0, stream>>>(cnt, bsum, N);
    k_bscan<<<1, 256, 0, stream>>>(bsum, bpre, NB);
    k_offs<<<NB, 256, 0, stream>>>(cnt, bpre, offs, N, E);
    k_fill2<<<gE, 256, 0, stream>>>(src, dst, offs, rank, csr2, E);

    // ---- layer 1: x -> h1
    k_mgemm128<<<gG, 256, 0, stream>>>(xb, w1t, featb, N);
    k_elr_bf<4, 32><<<g4, 256, 0, stream>>>(featb, al1, ar1, el, er, N * 4);
    k_ew4<<<gE, 256, 0, stream>>>(csr2, el, er, aw, E);
    k_denom4<<<gN, 256, 0, stream>>>(aw, offs, inv, N);
    k_aggr128d<false, true><<<gA, 256, 0, stream>>>(featb, csr2, offs, aw, inv, b1,
                                                    nullptr, h1b, h1f, N);

    // ---- layer 2: h1 -> h2
    k_mgemm128<<<gG, 256, 0, stream>>>(h1b, w2t, featb, N);
    k_elr_bf<4, 32><<<g4, 256, 0, stream>>>(featb, al2, ar2, el, er, N * 4);
    k_ew4<<<gE, 256, 0, stream>>>(csr2, el, er, aw, E);
    k_denom4<<<gN, 256, 0, stream>>>(aw, offs, inv, N);
    k_aggr128d<true, false><<<gA, 256, 0, stream>>>(featb, csr2, offs, aw, inv, b2,
                                                    h1f, h2b, nullptr, N);

    // ---- layer 3: weights -> fused aggregate+tail GEMM (z stays in LDS)
    k_elr3<<<g6, 256, 0, stream>>>(h2b, al3c, ar3c, el, er, N * 6);
    k_ew6<<<gE, 256, 0, stream>>>(csr2, el, er, aw, E);
    k_denom6<<<gN, 256, 0, stream>>>(aw, offs, inv, N);
    k_fuse3b<<<gF, 256, 0, stream>>>(h2b, csr2, offs, aw, inv, bt2, mb, out, N);
}

// Round 15
// 397.264 us; speedup vs baseline: 1.1250x; 1.0302x over previous
//
#include <hip/hip_runtime.h>
#include <hip/hip_bf16.h>

// DistGAT: 3-layer GAT, N=50000 nodes, E=800000 edges.
// R15: revert the layer-3 fusion (both granularities lost to the split pair:
//      R13 158us @1blk/CU, R14 122us @28% occ vs split 102us — the gather
//      phase needs high occupancy that the MFMA phase's LDS forbids).
//      = R12 (best measured, 390us) + k_mtail3 retiled 128->64 rows:
//      48KB LDS -> 3 blocks/CU, 782 blocks -> balanced ~3/CU grid (was 391
//      blocks = 2-wave dispatch with 65%-empty tail), wave owns 16x64 strip.
// Everything else identical to R12.

#define NODES 50000
#define EDGES 800000
#define NEG 0.2f

typedef __attribute__((ext_vector_type(8))) short bh8;
typedef __attribute__((ext_vector_type(4))) float f4;

__device__ __forceinline__ float leaky(float e) { return e > 0.f ? e : NEG * e; }
__device__ __forceinline__ float blo(unsigned u) { return __uint_as_float(u << 16); }
__device__ __forceinline__ float bhi(unsigned u) { return __uint_as_float(u & 0xffff0000u); }
__device__ __forceinline__ unsigned f2bf(float f) {  // RNE, low 16 bits valid
    unsigned u = __float_as_uint(f);
    return (u + 0x7fffu + ((u >> 16) & 1u)) >> 16;
}
// pack two f32 into one bf16x2 word for hi and for lo (exact remainder)
__device__ __forceinline__ void pk2(float a, float b, unsigned& hi, unsigned& lo) {
    unsigned ha = f2bf(a), hb = f2bf(b);
    float ra = a - __uint_as_float(ha << 16);
    float rb = b - __uint_as_float(hb << 16);
    hi = ha | (hb << 16);
    lo = f2bf(ra) | (f2bf(rb) << 16);
}

// swizzled byte offset in a [rows][128-bf16] LDS tile (row stride 256 B)
#define SW(row, bc) (((row) << 8) + ((bc) ^ (((row) & 7) << 4)))

// ---------------------------------------------------------------- prep
__global__ void k_cast(const float* __restrict__ in, unsigned short* __restrict__ outb, int n4) {
    int gid = blockIdx.x * blockDim.x + threadIdx.x;
    if (gid >= n4) return;
    float4 v = *reinterpret_cast<const float4*>(in + (size_t)gid * 4);
    unsigned u0 = f2bf(v.x) | (f2bf(v.y) << 16);
    unsigned u1 = f2bf(v.z) | (f2bf(v.w) << 16);
    *reinterpret_cast<uint2*>(outb + (size_t)gid * 4) = make_uint2(u0, u1);
}

__global__ void k_prepw(const float* __restrict__ W, unsigned short* __restrict__ WT, int F) {
    int gid = blockIdx.x * blockDim.x + threadIdx.x;
    if (gid >= 128 * F) return;
    int k = gid / F, f = gid - k * F;
    WT[(size_t)f * 128 + k] = (unsigned short)f2bf(W[gid]);
}

__global__ void k_prep_bt2(const float* __restrict__ W3, const float* __restrict__ Wres3,
                           unsigned short* __restrict__ BT2) {
    int gid = blockIdx.x * blockDim.x + threadIdx.x;
    if (gid >= 64 * 896) return;
    int d = gid / 896, k = gid - d * 896;
    float v;
    if (k < 768) {
        v = W3[(size_t)(k & 127) * 384 + (k >> 7) * 64 + d];
    } else {
        int kr = k - 768;
        v = 0.f;
#pragma unroll
        for (int h = 0; h < 6; ++h) v += Wres3[(size_t)kr * 384 + h * 64 + d];
    }
    BT2[(size_t)d * 896 + k] = (unsigned short)f2bf(v);
}

__global__ void k_prep_alr3(const float* __restrict__ W3, const float* __restrict__ al3,
                            const float* __restrict__ ar3, float* __restrict__ al3c,
                            float* __restrict__ ar3c) {
    int gid = blockIdx.x * blockDim.x + threadIdx.x;
    if (gid >= 1536) return;
    int g = (gid < 768) ? gid : gid - 768;
    int h = g >> 7, k = g & 127;
    const float* a = (gid < 768) ? al3 : ar3;
    float s = 0.f;
#pragma unroll
    for (int d = 0; d < 64; ++d) s += W3[(size_t)k * 384 + h * 64 + d] * a[h * 64 + d];
    if (gid < 768) al3c[g] = s; else ar3c[g] = s;
}

__global__ void k_prep_mb(const float* __restrict__ b3, float* __restrict__ mb) {
    int d = threadIdx.x;
    if (d >= 64) return;
    float s = 0.f;
#pragma unroll
    for (int h = 0; h < 6; ++h) s += b3[h * 64 + d];
    mb[d] = s * (1.f / 6.f);
}

// ---------------------------------------------------------------- CSR build
__global__ void k_hist2(const int* __restrict__ dst, int* __restrict__ cnt,
                        int* __restrict__ rank, int e) {
    int gid = blockIdx.x * blockDim.x + threadIdx.x;
    if (gid < e) rank[gid] = atomicAdd(&cnt[dst[gid]], 1);
}

__global__ void k_bsum(const int* __restrict__ deg, int* __restrict__ bsum, int n) {
    __shared__ int sm[256];
    int t = threadIdx.x;
    int i = blockIdx.x * 256 + t;
    sm[t] = (i < n) ? deg[i] : 0;
    __syncthreads();
#pragma unroll
    for (int off = 128; off > 0; off >>= 1) {
        if (t < off) sm[t] += sm[t + off];
        __syncthreads();
    }
    if (t == 0) bsum[blockIdx.x] = sm[0];
}

__global__ void k_bscan(const int* __restrict__ bsum, int* __restrict__ bpre, int nb) {
    __shared__ int sm[256];
    int t = threadIdx.x;
    int v = (t < nb) ? bsum[t] : 0;
    sm[t] = v;
    __syncthreads();
    for (int off = 1; off < 256; off <<= 1) {
        int u = (t >= off) ? sm[t - off] : 0;
        __syncthreads();
        sm[t] += u;
        __syncthreads();
    }
    if (t < nb) bpre[t] = sm[t] - v;
}

__global__ void k_offs(const int* __restrict__ deg, const int* __restrict__ bpre,
                       int* __restrict__ offs, int n, int e) {
    __shared__ int sm[256];
    int t = threadIdx.x;
    int i = blockIdx.x * 256 + t;
    int v = (i < n) ? deg[i] : 0;
    sm[t] = v;
    __syncthreads();
    for (int off = 1; off < 256; off <<= 1) {
        int u = (t >= off) ? sm[t - off] : 0;
        __syncthreads();
        sm[t] += u;
        __syncthreads();
    }
    if (i < n) offs[i] = bpre[blockIdx.x] + sm[t] - v;
    if (i == 0) offs[n] = e;
}

__global__ void k_fill2(const int* __restrict__ src, const int* __restrict__ dst,
                        const int* __restrict__ offs, const int* __restrict__ rank,
                        int2* __restrict__ csr2, int e) {
    int gid = blockIdx.x * blockDim.x + threadIdx.x;
    if (gid < e) {
        int d = dst[gid];
        int pos = offs[d] + rank[gid];
        csr2[pos] = make_int2(src[gid], d);
    }
}

// ---------------------------------------------------------------- edge weights (bf16)
__global__ void k_ew4(const int2* __restrict__ csr2, const float* __restrict__ el,
                      const float* __restrict__ er, unsigned short* __restrict__ aw, int e) {
    int gid = blockIdx.x * blockDim.x + threadIdx.x;
    if (gid >= e) return;
    int2 sd = csr2[gid];
    float4 l4 = *reinterpret_cast<const float4*>(el + (size_t)sd.x * 4);
    float4 r4 = *reinterpret_cast<const float4*>(er + (size_t)sd.y * 4);
    float w0 = __expf(leaky(l4.x + r4.x));
    float w1 = __expf(leaky(l4.y + r4.y));
    float w2 = __expf(leaky(l4.z + r4.z));
    float w3 = __expf(leaky(l4.w + r4.w));
    unsigned u0 = f2bf(w0) | (f2bf(w1) << 16);
    unsigned u1 = f2bf(w2) | (f2bf(w3) << 16);
    *reinterpret_cast<uint2*>(aw + (size_t)gid * 4) = make_uint2(u0, u1);
}

__global__ void k_ew6(const int2* __restrict__ csr2, const float* __restrict__ el,
                      const float* __restrict__ er, unsigned short* __restrict__ aw, int e) {
    int gid = blockIdx.x * blockDim.x + threadIdx.x;
    if (gid >= e) return;
    int2 sd = csr2[gid];
    const float2* lp = reinterpret_cast<const float2*>(el + (size_t)sd.x * 6);
    const float2* rp = reinterpret_cast<const float2*>(er + (size_t)sd.y * 6);
    float2 l0 = lp[0], l1 = lp[1], l2 = lp[2];
    float2 r0 = rp[0], r1 = rp[1], r2 = rp[2];
    unsigned w01 = f2bf(__expf(leaky(l0.x + r0.x))) | (f2bf(__expf(leaky(l0.y + r0.y))) << 16);
    unsigned w23 = f2bf(__expf(leaky(l1.x + r1.x))) | (f2bf(__expf(leaky(l1.y + r1.y))) << 16);
    unsigned w45 = f2bf(__expf(leaky(l2.x + r2.x))) | (f2bf(__expf(leaky(l2.y + r2.y))) << 16);
    unsigned char* wb = reinterpret_cast<unsigned char*>(aw) + (size_t)gid * 12;
    *reinterpret_cast<unsigned*>(wb + 0) = w01;
    *reinterpret_cast<unsigned*>(wb + 4) = w23;
    *reinterpret_cast<unsigned*>(wb + 8) = w45;
}

// ---------------------------------------------------------------- denominators
__global__ void k_denom4(const unsigned short* __restrict__ aw,
                         const int* __restrict__ offs, float* __restrict__ inv4, int n) {
    int gid = blockIdx.x * blockDim.x + threadIdx.x;
    if (gid >= n) return;
    int o0 = offs[gid], o1 = offs[gid + 1];
    float s0 = 0.f, s1 = 0.f, s2 = 0.f, s3 = 0.f;
    for (int p = o0; p < o1; ++p) {
        uint2 wu = *reinterpret_cast<const uint2*>(aw + (size_t)p * 4);
        s0 += blo(wu.x); s1 += bhi(wu.x);
        s2 += blo(wu.y); s3 += bhi(wu.y);
    }
    float4 r = (o1 > o0) ? make_float4(1.f / s0, 1.f / s1, 1.f / s2, 1.f / s3)
                         : make_float4(0.f, 0.f, 0.f, 0.f);
    *reinterpret_cast<float4*>(inv4 + (size_t)gid * 4) = r;
}

__global__ void k_denom6(const unsigned short* __restrict__ aw,
                         const int* __restrict__ offs, float* __restrict__ inv6, int n) {
    int gid = blockIdx.x * blockDim.x + threadIdx.x;
    if (gid >= n) return;
    int o0 = offs[gid], o1 = offs[gid + 1];
    float s[6] = {0.f, 0.f, 0.f, 0.f, 0.f, 0.f};
    const unsigned char* awb = reinterpret_cast<const unsigned char*>(aw);
    for (int p = o0; p < o1; ++p) {
        const unsigned char* wb = awb + (size_t)p * 12;
        unsigned w01 = *reinterpret_cast<const unsigned*>(wb + 0);
        unsigned w23 = *reinterpret_cast<const unsigned*>(wb + 4);
        unsigned w45 = *reinterpret_cast<const unsigned*>(wb + 8);
        s[0] += blo(w01); s[1] += bhi(w01);
        s[2] += blo(w23); s[3] += bhi(w23);
        s[4] += blo(w45); s[5] += bhi(w45);
    }
    bool has = o1 > o0;
    float* o = inv6 + (size_t)gid * 6;
#pragma unroll
    for (int h = 0; h < 6; ++h) o[h] = has ? 1.f / s[h] : 0.f;
}

// ---------------------------------------------------------------- MFMA GEMM (layers 1-2)
__global__ __launch_bounds__(256) void k_mgemm128(const unsigned short* __restrict__ A,
                                                  const unsigned short* __restrict__ BT,
                                                  unsigned short* __restrict__ C0,
                                                  int nrows) {
    __shared__ char Alds[64 * 256];
    __shared__ char Blds[64 * 256];
    const int t  = threadIdx.x;
    const int n0 = blockIdx.x * 64;
    const int w  = t >> 6;
    const int l  = t & 63;
    const int lr = l & 15;
    const int lk = l >> 4;

    {
        int col8 = (t & 15) * 8;
        int bc   = col8 * 2;
#pragma unroll
        for (int p = 0; p < 4; ++p) {
            int row = p * 16 + (t >> 4);
            int gr  = n0 + row;
            uint4 v = make_uint4(0, 0, 0, 0);
            if (gr < nrows) v = *reinterpret_cast<const uint4*>(A + (size_t)gr * 128 + col8);
            *reinterpret_cast<uint4*>(Alds + SW(row, bc)) = v;
        }
    }

    const int rbase = (w & 1) * 32;
    const int cbase = (w >> 1) * 32;

    for (int ct = 0; ct < 2; ++ct) {
        __syncthreads();
        {
            int col8 = (t & 15) * 8;
            int bc   = col8 * 2;
#pragma unroll
            for (int p = 0; p < 4; ++p) {
                int row = p * 16 + (t >> 4);
                uint4 v = *reinterpret_cast<const uint4*>(BT + (size_t)(ct * 64 + row) * 128 + col8);
                *reinterpret_cast<uint4*>(Blds + SW(row, bc)) = v;
            }
        }
        __syncthreads();

        f4 acc00 = {0.f, 0.f, 0.f, 0.f}, acc01 = {0.f, 0.f, 0.f, 0.f};
        f4 acc10 = {0.f, 0.f, 0.f, 0.f}, acc11 = {0.f, 0.f, 0.f, 0.f};
#pragma unroll
        for (int kk = 0; kk < 4; ++kk) {
            int bck = kk * 64 + lk * 16;
            bh8 a0 = *reinterpret_cast<const bh8*>(Alds + SW(rbase + lr, bck));
            bh8 a1 = *reinterpret_cast<const bh8*>(Alds + SW(rbase + 16 + lr, bck));
            bh8 b0 = *reinterpret_cast<const bh8*>(Blds + SW(cbase + lr, bck));
            bh8 b1 = *reinterpret_cast<const bh8*>(Blds + SW(cbase + 16 + lr, bck));
            acc00 = __builtin_amdgcn_mfma_f32_16x16x32_bf16(a0, b0, acc00, 0, 0, 0);
            acc01 = __builtin_amdgcn_mfma_f32_16x16x32_bf16(a0, b1, acc01, 0, 0, 0);
            acc10 = __builtin_amdgcn_mfma_f32_16x16x32_bf16(a1, b0, acc10, 0, 0, 0);
            acc11 = __builtin_amdgcn_mfma_f32_16x16x32_bf16(a1, b1, acc11, 0, 0, 0);
        }

        const f4* accs[4] = {&acc00, &acc01, &acc10, &acc11};
#pragma unroll
        for (int m = 0; m < 2; ++m) {
#pragma unroll
            for (int j = 0; j < 4; ++j) {
                int gr = n0 + rbase + m * 16 + lk * 4 + j;
                if (gr >= nrows) continue;
#pragma unroll
                for (int n = 0; n < 2; ++n) {
                    float v = (*accs[m * 2 + n])[j];
                    C0[(size_t)gr * 128 + ct * 64 + cbase + n * 16 + lr] = (unsigned short)f2bf(v);
                }
            }
        }
    }
}

// ---------------------------------------------------------------- tail GEMM (layer 3)
// out[N,64] = ((Zhi+Zlo)[N,768] @ M + h2 @ Wres3sum)/6 + mb.  64-row blocks:
// 48KB LDS -> 3 blocks/CU, 782 blocks (balanced grid). Wave w owns rows
// w*16..+15 x all 64 cols. Z read f32, hi/lo bf16-split during staging.
__global__ __launch_bounds__(256) void k_mtail3(const float* __restrict__ zf,
                                                const unsigned short* __restrict__ h2b,
                                                const unsigned short* __restrict__ BT2,
                                                const float* __restrict__ mb,
                                                float* __restrict__ out, int nrows) {
    __shared__ char Ahi[64 * 256];   // 16 KB
    __shared__ char Alo[64 * 256];   // 16 KB
    __shared__ char Blds[64 * 256];  // 16 KB
    const int t  = threadIdx.x;
    const int n0 = blockIdx.x * 64;
    const int w  = t >> 6;
    const int l  = t & 63;
    const int lr = l & 15;
    const int lk = l >> 4;
    const int rbase = w * 16;

    f4 acc0 = {0,0,0,0}, acc1 = {0,0,0,0}, acc2 = {0,0,0,0}, acc3 = {0,0,0,0};

    for (int kt = 0; kt < 7; ++kt) {
        __syncthreads();
        {
            int col8 = (t & 15) * 8;
            int bc   = col8 * 2;
            int rr   = t >> 4;
#pragma unroll
            for (int p = 0; p < 4; ++p) {   // A: 64 rows
                int row = p * 16 + rr;
                int gr  = n0 + row;
                if (kt < 6) {
                    float4 v0 = make_float4(0.f, 0.f, 0.f, 0.f);
                    float4 v1 = make_float4(0.f, 0.f, 0.f, 0.f);
                    if (gr < nrows) {
                        const float* ap = zf + (size_t)gr * 768 + kt * 128 + col8;
                        v0 = *reinterpret_cast<const float4*>(ap);
                        v1 = *reinterpret_cast<const float4*>(ap + 4);
                    }
                    unsigned h0, l0, h1, l1, h2_, l2_, h3, l3;
                    pk2(v0.x, v0.y, h0, l0);
                    pk2(v0.z, v0.w, h1, l1);
                    pk2(v1.x, v1.y, h2_, l2_);
                    pk2(v1.z, v1.w, h3, l3);
                    *reinterpret_cast<uint4*>(Ahi + SW(row, bc)) = make_uint4(h0, h1, h2_, h3);
                    *reinterpret_cast<uint4*>(Alo + SW(row, bc)) = make_uint4(l0, l1, l2_, l3);
                } else {
                    uint4 v = make_uint4(0, 0, 0, 0);
                    if (gr < nrows)
                        v = *reinterpret_cast<const uint4*>(h2b + (size_t)gr * 128 + col8);
                    *reinterpret_cast<uint4*>(Ahi + SW(row, bc)) = v;
                }
            }
#pragma unroll
            for (int p = 0; p < 4; ++p) {   // B: 64 out-cols
                int row = p * 16 + rr;
                uint4 v = *reinterpret_cast<const uint4*>(BT2 + (size_t)row * 896 + kt * 128 + col8);
                *reinterpret_cast<uint4*>(Blds + SW(row, bc)) = v;
            }
        }
        __syncthreads();
#pragma unroll
        for (int kk = 0; kk < 4; ++kk) {
            int bck = kk * 64 + lk * 16;
            bh8 b0 = *reinterpret_cast<const bh8*>(Blds + SW(0 * 16 + lr, bck));
            bh8 b1 = *reinterpret_cast<const bh8*>(Blds + SW(1 * 16 + lr, bck));
            bh8 b2 = *reinterpret_cast<const bh8*>(Blds + SW(2 * 16 + lr, bck));
            bh8 b3 = *reinterpret_cast<const bh8*>(Blds + SW(3 * 16 + lr, bck));
            bh8 a = *reinterpret_cast<const bh8*>(Ahi + SW(rbase + lr, bck));
            acc0 = __builtin_amdgcn_mfma_f32_16x16x32_bf16(a, b0, acc0, 0, 0, 0);
            acc1 = __builtin_amdgcn_mfma_f32_16x16x32_bf16(a, b1, acc1, 0, 0, 0);
            acc2 = __builtin_amdgcn_mfma_f32_16x16x32_bf16(a, b2, acc2, 0, 0, 0);
            acc3 = __builtin_amdgcn_mfma_f32_16x16x32_bf16(a, b3, acc3, 0, 0, 0);
            if (kt < 6) {
                bh8 c = *reinterpret_cast<const bh8*>(Alo + SW(rbase + lr, bck));
                acc0 = __builtin_amdgcn_mfma_f32_16x16x32_bf16(c, b0, acc0, 0, 0, 0);
                acc1 = __builtin_amdgcn_mfma_f32_16x16x32_bf16(c, b1, acc1, 0, 0, 0);
                acc2 = __builtin_amdgcn_mfma_f32_16x16x32_bf16(c, b2, acc2, 0, 0, 0);
                acc3 = __builtin_amdgcn_mfma_f32_16x16x32_bf16(c, b3, acc3, 0, 0, 0);
            }
        }
    }

    const f4* accs[4] = {&acc0, &acc1, &acc2, &acc3};
#pragma unroll
    for (int j = 0; j < 4; ++j) {
        int gr = n0 + rbase + lk * 4 + j;
        if (gr >= nrows) continue;
#pragma unroll
        for (int n = 0; n < 4; ++n) {
            int col = n * 16 + lr;
            float v = (*accs[n])[j];
            out[(size_t)gr * 64 + col] = v * (1.f / 6.f) + mb[col];
        }
    }
}

// ---------------------------------------------------------------- el / er, layers 1-2
template <int H, int D>
__global__ void k_elr_bf(const unsigned short* __restrict__ feat,
                         const float* __restrict__ al, const float* __restrict__ ar,
                         float* __restrict__ el, float* __restrict__ er, int total) {
    int gid = blockIdx.x * blockDim.x + threadIdx.x;
    if (gid >= total) return;
    int n = gid / H, h = gid - n * H;
    const uint4* f = reinterpret_cast<const uint4*>(feat + (size_t)n * (H * D) + h * D);
    const float4* a = reinterpret_cast<const float4*>(al + h * D);
    const float4* r = reinterpret_cast<const float4*>(ar + h * D);
    float sl = 0.f, sr = 0.f;
#pragma unroll
    for (int j = 0; j < D / 8; ++j) {
        uint4 v = f[j];
        float4 a0 = a[2 * j], a1 = a[2 * j + 1];
        float4 r0 = r[2 * j], r1 = r[2 * j + 1];
        float x0 = blo(v.x), x1 = bhi(v.x), x2 = blo(v.y), x3 = bhi(v.y);
        float x4 = blo(v.z), x5 = bhi(v.z), x6 = blo(v.w), x7 = bhi(v.w);
        sl += x0 * a0.x + x1 * a0.y + x2 * a0.z + x3 * a0.w +
              x4 * a1.x + x5 * a1.y + x6 * a1.z + x7 * a1.w;
        sr += x0 * r0.x + x1 * r0.y + x2 * r0.z + x3 * r0.w +
              x4 * r1.x + x5 * r1.y + x6 * r1.z + x7 * r1.w;
    }
    el[gid] = sl;
    er[gid] = sr;
}

// ---------------------------------------------------------------- el / er, layer 3
__global__ void k_elr3(const unsigned short* __restrict__ h2b,
                       const float* __restrict__ al3c, const float* __restrict__ ar3c,
                       float* __restrict__ el, float* __restrict__ er, int total) {
    int gid = blockIdx.x * blockDim.x + threadIdx.x;
    if (gid >= total) return;
    int n = gid / 6, h = gid - n * 6;
    const uint4* f = reinterpret_cast<const uint4*>(h2b + (size_t)n * 128);
    const float4* a = reinterpret_cast<const float4*>(al3c + h * 128);
    const float4* r = reinterpret_cast<const float4*>(ar3c + h * 128);
    float sl = 0.f, sr = 0.f;
#pragma unroll
    for (int j = 0; j < 16; ++j) {
        uint4 v = f[j];
        float4 a0 = a[2 * j], a1 = a[2 * j + 1];
        float4 r0 = r[2 * j], r1 = r[2 * j + 1];
        float x0 = blo(v.x), x1 = bhi(v.x), x2 = blo(v.y), x3 = bhi(v.y);
        float x4 = blo(v.z), x5 = bhi(v.z), x6 = blo(v.w), x7 = bhi(v.w);
        sl += x0 * a0.x + x1 * a0.y + x2 * a0.z + x3 * a0.w +
              x4 * a1.x + x5 * a1.y + x6 * a1.z + x7 * a1.w;
        sr += x0 * r0.x + x1 * r0.y + x2 * r0.z + x3 * r0.w +
              x4 * r1.x + x5 * r1.y + x6 * r1.z + x7 * r1.w;
    }
    el[gid] = sl;
    er[gid] = sr;
}

// ---------------------------------------------------------------- aggregation, layers 1-2
template <bool HASRES, bool WRITEF32>
__global__ __launch_bounds__(256) void k_aggr128d(
    const unsigned short* __restrict__ feat, const int2* __restrict__ csr2,
    const int* __restrict__ offs, const unsigned short* __restrict__ aw,
    const float* __restrict__ inv4, const float* __restrict__ bias,
    const float* __restrict__ resf, unsigned short* __restrict__ outb,
    float* __restrict__ outf, int nnodes) {
    int node = blockIdx.x * 4 + (threadIdx.x >> 6);
    if (node >= nnodes) return;
    int l = threadIdx.x & 63;
    int half = l >> 5;
    int ll = l & 31;
    int h = ll >> 3;
    int o0 = offs[node], o1 = offs[node + 1];
    float acc0 = 0.f, acc1 = 0.f, acc2 = 0.f, acc3 = 0.f;
    int nt = (o1 - o0 + 1) >> 1;
#pragma unroll 2
    for (int t = 0; t < nt; ++t) {
        int ei = o0 + 2 * t + half;
        int pos = (ei < o1) ? ei : EDGES;      // dummy slot: w == 0
        uint2 wu = *reinterpret_cast<const uint2*>(aw + (size_t)pos * 4);
        unsigned uw = (h & 2) ? wu.y : wu.x;
        float w = (h & 1) ? bhi(uw) : blo(uw);
        int sidx = csr2[pos].x;
        uint2 u = *reinterpret_cast<const uint2*>(feat + (size_t)sidx * 128 + 4 * ll);
        acc0 = fmaf(w, blo(u.x), acc0);
        acc1 = fmaf(w, bhi(u.x), acc1);
        acc2 = fmaf(w, blo(u.y), acc2);
        acc3 = fmaf(w, bhi(u.y), acc3);
    }
    acc0 += __shfl_xor(acc0, 32);
    acc1 += __shfl_xor(acc1, 32);
    acc2 += __shfl_xor(acc2, 32);
    acc3 += __shfl_xor(acc3, 32);
    float inv = inv4[(size_t)node * 4 + h];
    int f = 4 * ll;
    float4 bi = *reinterpret_cast<const float4*>(bias + f);
    float r0 = acc0 * inv + bi.x;
    float r1 = acc1 * inv + bi.y;
    float r2 = acc2 * inv + bi.z;
    float r3 = acc3 * inv + bi.w;
    if (HASRES) {
        float4 rv = *reinterpret_cast<const float4*>(resf + (size_t)node * 128 + f);
        r0 += rv.x; r1 += rv.y; r2 += rv.z; r3 += rv.w;
    }
    r0 = (r0 > 0.f) ? r0 : (__expf(r0) - 1.f);
    r1 = (r1 > 0.f) ? r1 : (__expf(r1) - 1.f);
    r2 = (r2 > 0.f) ? r2 : (__expf(r2) - 1.f);
    r3 = (r3 > 0.f) ? r3 : (__expf(r3) - 1.f);
    if (half == 0) {
        unsigned u0 = f2bf(r0) | (f2bf(r1) << 16);
        unsigned u1 = f2bf(r2) | (f2bf(r3) << 16);
        *reinterpret_cast<uint2*>(outb + (size_t)node * 128 + f) = make_uint2(u0, u1);
        if (WRITEF32)
            *reinterpret_cast<float4*>(outf + (size_t)node * 128 + f) =
                make_float4(r0, r1, r2, r3);
    }
}

// ---------------------------------------------------------------- aggregation, layer 3 (z-form)
__global__ __launch_bounds__(256) void k_aggrZ3(
    const unsigned short* __restrict__ h2b, const int2* __restrict__ csr2,
    const int* __restrict__ offs, const unsigned short* __restrict__ aw6,
    const float* __restrict__ inv6, float* __restrict__ zf, int nnodes) {
    int node = blockIdx.x * 4 + (threadIdx.x >> 6);
    if (node >= nnodes) return;
    int l = threadIdx.x & 63;
    int half = l >> 5;
    int ll = l & 31;
    float acc[6][4];
#pragma unroll
    for (int h = 0; h < 6; ++h)
#pragma unroll
        for (int j = 0; j < 4; ++j) acc[h][j] = 0.f;
    int o0 = offs[node], o1 = offs[node + 1];
    int nt = (o1 - o0 + 1) >> 1;
    const unsigned char* awb = reinterpret_cast<const unsigned char*>(aw6);
#pragma unroll 2
    for (int t = 0; t < nt; ++t) {
        int ei = o0 + 2 * t + half;
        int pos = (ei < o1) ? ei : EDGES;      // dummy slot: w == 0
        const unsigned char* wb = awb + (size_t)pos * 12;
        unsigned w01 = *reinterpret_cast<const unsigned*>(wb + 0);
        unsigned w23 = *reinterpret_cast<const unsigned*>(wb + 4);
        unsigned w45 = *reinterpret_cast<const unsigned*>(wb + 8);
        float wv[6] = {blo(w01), bhi(w01), blo(w23), bhi(w23), blo(w45), bhi(w45)};
        int sidx = csr2[pos].x;
        uint2 u = *reinterpret_cast<const uint2*>(h2b + (size_t)sidx * 128 + 4 * ll);
        float f0 = blo(u.x), f1 = bhi(u.x), f2 = blo(u.y), f3 = bhi(u.y);
#pragma unroll
        for (int h = 0; h < 6; ++h) {
            acc[h][0] = fmaf(wv[h], f0, acc[h][0]);
            acc[h][1] = fmaf(wv[h], f1, acc[h][1]);
            acc[h][2] = fmaf(wv[h], f2, acc[h][2]);
            acc[h][3] = fmaf(wv[h], f3, acc[h][3]);
        }
    }
#pragma unroll
    for (int h = 0; h < 6; ++h)
#pragma unroll
        for (int j = 0; j < 4; ++j) acc[h][j] += __shfl_xor(acc[h][j], 32);
    if (half == 0) {
        float2 i01 = *reinterpret_cast<const float2*>(inv6 + (size_t)node * 6 + 0);
        float2 i23 = *reinterpret_cast<const float2*>(inv6 + (size_t)node * 6 + 2);
        float2 i45 = *reinterpret_cast<const float2*>(inv6 + (size_t)node * 6 + 4);
        float iv[6] = {i01.x, i01.y, i23.x, i23.y, i45.x, i45.y};
#pragma unroll
        for (int h = 0; h < 6; ++h) {
            *reinterpret_cast<float4*>(zf + (size_t)node * 768 + h * 128 + 4 * ll) =
                make_float4(acc[h][0] * iv[h], acc[h][1] * iv[h],
                            acc[h][2] * iv[h], acc[h][3] * iv[h]);
        }
    }
}

// ---------------------------------------------------------------- launch
extern "C" void kernel_launch(void* const* d_in, const int* in_sizes, int n_in,
                              void* d_out, int out_size, void* d_ws, size_t ws_size,
                              hipStream_t stream) {
    const float* x     = (const float*)d_in[0];
    const int*   src   = (const int*)d_in[1];
    const int*   dst   = (const int*)d_in[2];
    const float* W1    = (const float*)d_in[3];
    const float* al1   = (const float*)d_in[4];
    const float* ar1   = (const float*)d_in[5];
    const float* b1    = (const float*)d_in[6];
    const float* W2    = (const float*)d_in[7];
    const float* al2   = (const float*)d_in[8];
    const float* ar2   = (const float*)d_in[9];
    const float* b2    = (const float*)d_in[10];
    const float* W3    = (const float*)d_in[11];
    const float* al3   = (const float*)d_in[12];
    const float* ar3   = (const float*)d_in[13];
    const float* b3    = (const float*)d_in[14];
    const float* Wres3 = (const float*)d_in[15];
    float* out = (float*)d_out;

    const int N = NODES, E = EDGES;
    const int NB = (N + 255) / 256;

    char*  ws = (char*)d_ws;
    size_t o  = 0;
    auto alloc = [&](size_t bytes) {
        size_t r = o;
        o += (bytes + 255) & ~(size_t)255;
        return r;
    };
    // persistent (~33 MB)
    int*            offs  = (int*)(ws + alloc((size_t)(N + 1) * 4));
    int*            cnt   = (int*)(ws + alloc((size_t)N * 4));
    int2*           csr2  = (int2*)(ws + alloc((size_t)(E + 1) * 8));
    float*          el    = (float*)(ws + alloc((size_t)N * 6 * 4));
    float*          er    = (float*)(ws + alloc((size_t)N * 6 * 4));
    unsigned short* aw    = (unsigned short*)(ws + alloc((size_t)(E + 1) * 6 * 2));
    float*          inv   = (float*)(ws + alloc((size_t)N * 6 * 4));     // inv4/inv6
    unsigned short* h2b   = (unsigned short*)(ws + alloc((size_t)N * 128 * 2));
    unsigned short* w1t   = (unsigned short*)(ws + alloc((size_t)128 * 128 * 2));
    unsigned short* w2t   = (unsigned short*)(ws + alloc((size_t)128 * 128 * 2));
    unsigned short* bt2   = (unsigned short*)(ws + alloc((size_t)64 * 896 * 2));
    float*          al3c  = (float*)(ws + alloc((size_t)768 * 4));
    float*          ar3c  = (float*)(ws + alloc((size_t)768 * 4));
    float*          mb    = (float*)(ws + alloc((size_t)64 * 4));
    int*            bsum  = (int*)(ws + alloc((size_t)256 * 4));
    int*            bpre  = (int*)(ws + alloc((size_t)256 * 4));
    // union region (153.6 MB): L1/2 transients + rank alias zf (disjoint lifetimes)
    char* U = ws + alloc((size_t)N * 768 * 4);
    unsigned short* xb    = (unsigned short*)(U);                        // 12.8M
    unsigned short* featb = (unsigned short*)(U + (size_t)N * 128 * 2);  // 12.8M
    unsigned short* h1b   = (unsigned short*)(U + (size_t)N * 256 * 2);  // 12.8M
    float*          h1f   = (float*)(U + (size_t)N * 384 * 2);           // 25.6M (ends 64M)
    int*            rank  = (int*)(U + (size_t)64 * 1024 * 1024);        // 3.2M @64M, dead before zf
    float*          zf    = (float*)(U);                                 // 153.6M (layer 3)

    const int gE = (E + 255) / 256;
    const int g4 = (N * 4 + 255) / 256;
    const int g6 = (N * 6 + 255) / 256;
    const int gN = (N + 255) / 256;
    const int gA = (N + 3) / 4;
    const int gG = (N + 63) / 64;
    const int gT = (N + 63) / 64;   // 782 64-row tail blocks

    // ---- prep
    k_cast<<<(N * 128 / 4 + 255) / 256, 256, 0, stream>>>(x, xb, N * 128 / 4);
    k_prepw<<<(128 * 128 + 255) / 256, 256, 0, stream>>>(W1, w1t, 128);
    k_prepw<<<(128 * 128 + 255) / 256, 256, 0, stream>>>(W2, w2t, 128);
    k_prep_bt2<<<(64 * 896 + 255) / 256, 256, 0, stream>>>(W3, Wres3, bt2);
    k_prep_alr3<<<6, 256, 0, stream>>>(W3, al3, ar3, al3c, ar3c);
    k_prep_mb<<<1, 64, 0, stream>>>(b3, mb);

    // ---- dummy edge slot: csr2[E]={0,0}; aw zeroed at both layouts' index E
    hipMemsetAsync(csr2 + E, 0, 8, stream);
    hipMemsetAsync((char*)aw + (size_t)E * 8, 0, 8, stream);    // ew4 layout dummy
    hipMemsetAsync((char*)aw + (size_t)E * 12, 0, 12, stream);  // ew6 layout dummy

    // ---- CSR by dst: hist+rank (atomic), parallel scan, atomic-free fill
    hipMemsetAsync(cnt, 0, (size_t)N * 4, stream);
    k_hist2<<<gE, 256, 0, stream>>>(dst, cnt, rank, E);
    k_bsum<<<NB, 256, 0, stream>>>(cnt, bsum, N);
    k_bscan<<<1, 256, 0, stream>>>(bsum, bpre, NB);
    k_offs<<<NB, 256, 0, stream>>>(cnt, bpre, offs, N, E);
    k_fill2<<<gE, 256, 0, stream>>>(src, dst, offs, rank, csr2, E);

    // ---- layer 1: x -> h1
    k_mgemm128<<<gG, 256, 0, stream>>>(xb, w1t, featb, N);
    k_elr_bf<4, 32><<<g4, 256, 0, stream>>>(featb, al1, ar1, el, er, N * 4);
    k_ew4<<<gE, 256, 0, stream>>>(csr2, el, er, aw, E);
    k_denom4<<<gN, 256, 0, stream>>>(aw, offs, inv, N);
    k_aggr128d<false, true><<<gA, 256, 0, stream>>>(featb, csr2, offs, aw, inv, b1,
                                                    nullptr, h1b, h1f, N);

    // ---- layer 2: h1 -> h2
    k_mgemm128<<<gG, 256, 0, stream>>>(h1b, w2t, featb, N);
    k_elr_bf<4, 32><<<g4, 256, 0, stream>>>(featb, al2, ar2, el, er, N * 4);
    k_ew4<<<gE, 256, 0, stream>>>(csr2, el, er, aw, E);
    k_denom4<<<gN, 256, 0, stream>>>(aw, offs, inv, N);
    k_aggr128d<true, false><<<gA, 256, 0, stream>>>(featb, csr2, offs, aw, inv, b2,
                                                    h1f, h2b, nullptr, N);

    // ---- layer 3: weights -> z (f32) -> tail GEMM (64-row tiles)
    k_elr3<<<g6, 256, 0, stream>>>(h2b, al3c, ar3c, el, er, N * 6);
    k_ew6<<<gE, 256, 0, stream>>>(csr2, el, er, aw, E);
    k_denom6<<<gN, 256, 0, stream>>>(aw, offs, inv, N);
    k_aggrZ3<<<gA, 256, 0, stream>>>(h2b, csr2, offs, aw, inv, zf, N);
    k_mtail3<<<gT, 256, 0, stream>>>(zf, h2b, bt2, mb, out, N);
}

// Round 16
// 388.138 us; speedup vs baseline: 1.1514x; 1.0235x over previous
//
#include <hip/hip_runtime.h>
#include <hip/hip_bf16.h>

// DistGAT: 3-layer GAT, N=50000 nodes, E=800000 edges.
// R16: restore R12 exactly (best measured, 390us; R15's 64-row mtail retile
//      was neutral-negative) + one MLP tweak: unroll 4 (was 2) on the two
//      gather loops (k_aggrZ3, k_aggr128d) to double independent gathers in
//      flight per wave (aggrZ3 at 52% VALU / 54% HBM = latency-limited mix).

#define NODES 50000
#define EDGES 800000
#define NEG 0.2f

typedef __attribute__((ext_vector_type(8))) short bh8;
typedef __attribute__((ext_vector_type(4))) float f4;

__device__ __forceinline__ float leaky(float e) { return e > 0.f ? e : NEG * e; }
__device__ __forceinline__ float blo(unsigned u) { return __uint_as_float(u << 16); }
__device__ __forceinline__ float bhi(unsigned u) { return __uint_as_float(u & 0xffff0000u); }
__device__ __forceinline__ unsigned f2bf(float f) {  // RNE, low 16 bits valid
    unsigned u = __float_as_uint(f);
    return (u + 0x7fffu + ((u >> 16) & 1u)) >> 16;
}
// pack two f32 into one bf16x2 word for hi and for lo (exact remainder)
__device__ __forceinline__ void pk2(float a, float b, unsigned& hi, unsigned& lo) {
    unsigned ha = f2bf(a), hb = f2bf(b);
    float ra = a - __uint_as_float(ha << 16);
    float rb = b - __uint_as_float(hb << 16);
    hi = ha | (hb << 16);
    lo = f2bf(ra) | (f2bf(rb) << 16);
}

// swizzled byte offset in a [rows][128-bf16] LDS tile (row stride 256 B)
#define SW(row, bc) (((row) << 8) + ((bc) ^ (((row) & 7) << 4)))

// ---------------------------------------------------------------- prep
__global__ void k_cast(const float* __restrict__ in, unsigned short* __restrict__ outb, int n4) {
    int gid = blockIdx.x * blockDim.x + threadIdx.x;
    if (gid >= n4) return;
    float4 v = *reinterpret_cast<const float4*>(in + (size_t)gid * 4);
    unsigned u0 = f2bf(v.x) | (f2bf(v.y) << 16);
    unsigned u1 = f2bf(v.z) | (f2bf(v.w) << 16);
    *reinterpret_cast<uint2*>(outb + (size_t)gid * 4) = make_uint2(u0, u1);
}

__global__ void k_prepw(const float* __restrict__ W, unsigned short* __restrict__ WT, int F) {
    int gid = blockIdx.x * blockDim.x + threadIdx.x;
    if (gid >= 128 * F) return;
    int k = gid / F, f = gid - k * F;
    WT[(size_t)f * 128 + k] = (unsigned short)f2bf(W[gid]);
}

__global__ void k_prep_bt2(const float* __restrict__ W3, const float* __restrict__ Wres3,
                           unsigned short* __restrict__ BT2) {
    int gid = blockIdx.x * blockDim.x + threadIdx.x;
    if (gid >= 64 * 896) return;
    int d = gid / 896, k = gid - d * 896;
    float v;
    if (k < 768) {
        v = W3[(size_t)(k & 127) * 384 + (k >> 7) * 64 + d];
    } else {
        int kr = k - 768;
        v = 0.f;
#pragma unroll
        for (int h = 0; h < 6; ++h) v += Wres3[(size_t)kr * 384 + h * 64 + d];
    }
    BT2[(size_t)d * 896 + k] = (unsigned short)f2bf(v);
}

__global__ void k_prep_alr3(const float* __restrict__ W3, const float* __restrict__ al3,
                            const float* __restrict__ ar3, float* __restrict__ al3c,
                            float* __restrict__ ar3c) {
    int gid = blockIdx.x * blockDim.x + threadIdx.x;
    if (gid >= 1536) return;
    int g = (gid < 768) ? gid : gid - 768;
    int h = g >> 7, k = g & 127;
    const float* a = (gid < 768) ? al3 : ar3;
    float s = 0.f;
#pragma unroll
    for (int d = 0; d < 64; ++d) s += W3[(size_t)k * 384 + h * 64 + d] * a[h * 64 + d];
    if (gid < 768) al3c[g] = s; else ar3c[g] = s;
}

__global__ void k_prep_mb(const float* __restrict__ b3, float* __restrict__ mb) {
    int d = threadIdx.x;
    if (d >= 64) return;
    float s = 0.f;
#pragma unroll
    for (int h = 0; h < 6; ++h) s += b3[h * 64 + d];
    mb[d] = s * (1.f / 6.f);
}

// ---------------------------------------------------------------- CSR build
__global__ void k_hist2(const int* __restrict__ dst, int* __restrict__ cnt,
                        int* __restrict__ rank, int e) {
    int gid = blockIdx.x * blockDim.x + threadIdx.x;
    if (gid < e) rank[gid] = atomicAdd(&cnt[dst[gid]], 1);
}

__global__ void k_bsum(const int* __restrict__ deg, int* __restrict__ bsum, int n) {
    __shared__ int sm[256];
    int t = threadIdx.x;
    int i = blockIdx.x * 256 + t;
    sm[t] = (i < n) ? deg[i] : 0;
    __syncthreads();
#pragma unroll
    for (int off = 128; off > 0; off >>= 1) {
        if (t < off) sm[t] += sm[t + off];
        __syncthreads();
    }
    if (t == 0) bsum[blockIdx.x] = sm[0];
}

__global__ void k_bscan(const int* __restrict__ bsum, int* __restrict__ bpre, int nb) {
    __shared__ int sm[256];
    int t = threadIdx.x;
    int v = (t < nb) ? bsum[t] : 0;
    sm[t] = v;
    __syncthreads();
    for (int off = 1; off < 256; off <<= 1) {
        int u = (t >= off) ? sm[t - off] : 0;
        __syncthreads();
        sm[t] += u;
        __syncthreads();
    }
    if (t < nb) bpre[t] = sm[t] - v;
}

__global__ void k_offs(const int* __restrict__ deg, const int* __restrict__ bpre,
                       int* __restrict__ offs, int n, int e) {
    __shared__ int sm[256];
    int t = threadIdx.x;
    int i = blockIdx.x * 256 + t;
    int v = (i < n) ? deg[i] : 0;
    sm[t] = v;
    __syncthreads();
    for (int off = 1; off < 256; off <<= 1) {
        int u = (t >= off) ? sm[t - off] : 0;
        __syncthreads();
        sm[t] += u;
        __syncthreads();
    }
    if (i < n) offs[i] = bpre[blockIdx.x] + sm[t] - v;
    if (i == 0) offs[n] = e;
}

__global__ void k_fill2(const int* __restrict__ src, const int* __restrict__ dst,
                        const int* __restrict__ offs, const int* __restrict__ rank,
                        int2* __restrict__ csr2, int e) {
    int gid = blockIdx.x * blockDim.x + threadIdx.x;
    if (gid < e) {
        int d = dst[gid];
        int pos = offs[d] + rank[gid];
        csr2[pos] = make_int2(src[gid], d);
    }
}

// ---------------------------------------------------------------- edge weights (bf16)
__global__ void k_ew4(const int2* __restrict__ csr2, const float* __restrict__ el,
                      const float* __restrict__ er, unsigned short* __restrict__ aw, int e) {
    int gid = blockIdx.x * blockDim.x + threadIdx.x;
    if (gid >= e) return;
    int2 sd = csr2[gid];
    float4 l4 = *reinterpret_cast<const float4*>(el + (size_t)sd.x * 4);
    float4 r4 = *reinterpret_cast<const float4*>(er + (size_t)sd.y * 4);
    float w0 = __expf(leaky(l4.x + r4.x));
    float w1 = __expf(leaky(l4.y + r4.y));
    float w2 = __expf(leaky(l4.z + r4.z));
    float w3 = __expf(leaky(l4.w + r4.w));
    unsigned u0 = f2bf(w0) | (f2bf(w1) << 16);
    unsigned u1 = f2bf(w2) | (f2bf(w3) << 16);
    *reinterpret_cast<uint2*>(aw + (size_t)gid * 4) = make_uint2(u0, u1);
}

__global__ void k_ew6(const int2* __restrict__ csr2, const float* __restrict__ el,
                      const float* __restrict__ er, unsigned short* __restrict__ aw, int e) {
    int gid = blockIdx.x * blockDim.x + threadIdx.x;
    if (gid >= e) return;
    int2 sd = csr2[gid];
    const float2* lp = reinterpret_cast<const float2*>(el + (size_t)sd.x * 6);
    const float2* rp = reinterpret_cast<const float2*>(er + (size_t)sd.y * 6);
    float2 l0 = lp[0], l1 = lp[1], l2 = lp[2];
    float2 r0 = rp[0], r1 = rp[1], r2 = rp[2];
    unsigned w01 = f2bf(__expf(leaky(l0.x + r0.x))) | (f2bf(__expf(leaky(l0.y + r0.y))) << 16);
    unsigned w23 = f2bf(__expf(leaky(l1.x + r1.x))) | (f2bf(__expf(leaky(l1.y + r1.y))) << 16);
    unsigned w45 = f2bf(__expf(leaky(l2.x + r2.x))) | (f2bf(__expf(leaky(l2.y + r2.y))) << 16);
    unsigned char* wb = reinterpret_cast<unsigned char*>(aw) + (size_t)gid * 12;
    *reinterpret_cast<unsigned*>(wb + 0) = w01;
    *reinterpret_cast<unsigned*>(wb + 4) = w23;
    *reinterpret_cast<unsigned*>(wb + 8) = w45;
}

// ---------------------------------------------------------------- denominators
__global__ void k_denom4(const unsigned short* __restrict__ aw,
                         const int* __restrict__ offs, float* __restrict__ inv4, int n) {
    int gid = blockIdx.x * blockDim.x + threadIdx.x;
    if (gid >= n) return;
    int o0 = offs[gid], o1 = offs[gid + 1];
    float s0 = 0.f, s1 = 0.f, s2 = 0.f, s3 = 0.f;
    for (int p = o0; p < o1; ++p) {
        uint2 wu = *reinterpret_cast<const uint2*>(aw + (size_t)p * 4);
        s0 += blo(wu.x); s1 += bhi(wu.x);
        s2 += blo(wu.y); s3 += bhi(wu.y);
    }
    float4 r = (o1 > o0) ? make_float4(1.f / s0, 1.f / s1, 1.f / s2, 1.f / s3)
                         : make_float4(0.f, 0.f, 0.f, 0.f);
    *reinterpret_cast<float4*>(inv4 + (size_t)gid * 4) = r;
}

__global__ void k_denom6(const unsigned short* __restrict__ aw,
                         const int* __restrict__ offs, float* __restrict__ inv6, int n) {
    int gid = blockIdx.x * blockDim.x + threadIdx.x;
    if (gid >= n) return;
    int o0 = offs[gid], o1 = offs[gid + 1];
    float s[6] = {0.f, 0.f, 0.f, 0.f, 0.f, 0.f};
    const unsigned char* awb = reinterpret_cast<const unsigned char*>(aw);
    for (int p = o0; p < o1; ++p) {
        const unsigned char* wb = awb + (size_t)p * 12;
        unsigned w01 = *reinterpret_cast<const unsigned*>(wb + 0);
        unsigned w23 = *reinterpret_cast<const unsigned*>(wb + 4);
        unsigned w45 = *reinterpret_cast<const unsigned*>(wb + 8);
        s[0] += blo(w01); s[1] += bhi(w01);
        s[2] += blo(w23); s[3] += bhi(w23);
        s[4] += blo(w45); s[5] += bhi(w45);
    }
    bool has = o1 > o0;
    float* o = inv6 + (size_t)gid * 6;
#pragma unroll
    for (int h = 0; h < 6; ++h) o[h] = has ? 1.f / s[h] : 0.f;
}

// ---------------------------------------------------------------- MFMA GEMM (layers 1-2)
__global__ __launch_bounds__(256) void k_mgemm128(const unsigned short* __restrict__ A,
                                                  const unsigned short* __restrict__ BT,
                                                  unsigned short* __restrict__ C0,
                                                  int nrows) {
    __shared__ char Alds[64 * 256];
    __shared__ char Blds[64 * 256];
    const int t  = threadIdx.x;
    const int n0 = blockIdx.x * 64;
    const int w  = t >> 6;
    const int l  = t & 63;
    const int lr = l & 15;
    const int lk = l >> 4;

    {
        int col8 = (t & 15) * 8;
        int bc   = col8 * 2;
#pragma unroll
        for (int p = 0; p < 4; ++p) {
            int row = p * 16 + (t >> 4);
            int gr  = n0 + row;
            uint4 v = make_uint4(0, 0, 0, 0);
            if (gr < nrows) v = *reinterpret_cast<const uint4*>(A + (size_t)gr * 128 + col8);
            *reinterpret_cast<uint4*>(Alds + SW(row, bc)) = v;
        }
    }

    const int rbase = (w & 1) * 32;
    const int cbase = (w >> 1) * 32;

    for (int ct = 0; ct < 2; ++ct) {
        __syncthreads();
        {
            int col8 = (t & 15) * 8;
            int bc   = col8 * 2;
#pragma unroll
            for (int p = 0; p < 4; ++p) {
                int row = p * 16 + (t >> 4);
                uint4 v = *reinterpret_cast<const uint4*>(BT + (size_t)(ct * 64 + row) * 128 + col8);
                *reinterpret_cast<uint4*>(Blds + SW(row, bc)) = v;
            }
        }
        __syncthreads();

        f4 acc00 = {0.f, 0.f, 0.f, 0.f}, acc01 = {0.f, 0.f, 0.f, 0.f};
        f4 acc10 = {0.f, 0.f, 0.f, 0.f}, acc11 = {0.f, 0.f, 0.f, 0.f};
#pragma unroll
        for (int kk = 0; kk < 4; ++kk) {
            int bck = kk * 64 + lk * 16;
            bh8 a0 = *reinterpret_cast<const bh8*>(Alds + SW(rbase + lr, bck));
            bh8 a1 = *reinterpret_cast<const bh8*>(Alds + SW(rbase + 16 + lr, bck));
            bh8 b0 = *reinterpret_cast<const bh8*>(Blds + SW(cbase + lr, bck));
            bh8 b1 = *reinterpret_cast<const bh8*>(Blds + SW(cbase + 16 + lr, bck));
            acc00 = __builtin_amdgcn_mfma_f32_16x16x32_bf16(a0, b0, acc00, 0, 0, 0);
            acc01 = __builtin_amdgcn_mfma_f32_16x16x32_bf16(a0, b1, acc01, 0, 0, 0);
            acc10 = __builtin_amdgcn_mfma_f32_16x16x32_bf16(a1, b0, acc10, 0, 0, 0);
            acc11 = __builtin_amdgcn_mfma_f32_16x16x32_bf16(a1, b1, acc11, 0, 0, 0);
        }

        const f4* accs[4] = {&acc00, &acc01, &acc10, &acc11};
#pragma unroll
        for (int m = 0; m < 2; ++m) {
#pragma unroll
            for (int j = 0; j < 4; ++j) {
                int gr = n0 + rbase + m * 16 + lk * 4 + j;
                if (gr >= nrows) continue;
#pragma unroll
                for (int n = 0; n < 2; ++n) {
                    float v = (*accs[m * 2 + n])[j];
                    C0[(size_t)gr * 128 + ct * 64 + cbase + n * 16 + lr] = (unsigned short)f2bf(v);
                }
            }
        }
    }
}

// ---------------------------------------------------------------- tail GEMM (layer 3)
// R12's 128-row version: out[N,64] = ((Zhi+Zlo)[N,768]@M + h2@Wres3sum)/6 + mb.
__global__ __launch_bounds__(256) void k_mtail3(const float* __restrict__ zf,
                                                const unsigned short* __restrict__ h2b,
                                                const unsigned short* __restrict__ BT2,
                                                const float* __restrict__ mb,
                                                float* __restrict__ out, int nrows) {
    __shared__ char Ahi[128 * 256];   // 32 KB
    __shared__ char Alo[128 * 256];   // 32 KB
    __shared__ char Blds[64 * 256];   // 16 KB
    const int t  = threadIdx.x;
    const int n0 = blockIdx.x * 128;
    const int w  = t >> 6;
    const int l  = t & 63;
    const int lr = l & 15;
    const int lk = l >> 4;
    const int rbase = w * 32;

    f4 acc00 = {0,0,0,0}, acc01 = {0,0,0,0}, acc02 = {0,0,0,0}, acc03 = {0,0,0,0};
    f4 acc10 = {0,0,0,0}, acc11 = {0,0,0,0}, acc12 = {0,0,0,0}, acc13 = {0,0,0,0};

    for (int kt = 0; kt < 7; ++kt) {
        __syncthreads();
        {
            int col8 = (t & 15) * 8;
            int bc   = col8 * 2;
            int rr   = t >> 4;
#pragma unroll
            for (int p = 0; p < 8; ++p) {   // A: 128 rows
                int row = p * 16 + rr;
                int gr  = n0 + row;
                if (kt < 6) {
                    float4 v0 = make_float4(0.f, 0.f, 0.f, 0.f);
                    float4 v1 = make_float4(0.f, 0.f, 0.f, 0.f);
                    if (gr < nrows) {
                        const float* ap = zf + (size_t)gr * 768 + kt * 128 + col8;
                        v0 = *reinterpret_cast<const float4*>(ap);
                        v1 = *reinterpret_cast<const float4*>(ap + 4);
                    }
                    unsigned h0, l0, h1, l1, h2_, l2_, h3, l3;
                    pk2(v0.x, v0.y, h0, l0);
                    pk2(v0.z, v0.w, h1, l1);
                    pk2(v1.x, v1.y, h2_, l2_);
                    pk2(v1.z, v1.w, h3, l3);
                    *reinterpret_cast<uint4*>(Ahi + SW(row, bc)) = make_uint4(h0, h1, h2_, h3);
                    *reinterpret_cast<uint4*>(Alo + SW(row, bc)) = make_uint4(l0, l1, l2_, l3);
                } else {
                    uint4 v = make_uint4(0, 0, 0, 0);
                    if (gr < nrows)
                        v = *reinterpret_cast<const uint4*>(h2b + (size_t)gr * 128 + col8);
                    *reinterpret_cast<uint4*>(Ahi + SW(row, bc)) = v;
                }
            }
#pragma unroll
            for (int p = 0; p < 4; ++p) {   // B: 64 out-cols
                int row = p * 16 + rr;
                uint4 v = *reinterpret_cast<const uint4*>(BT2 + (size_t)row * 896 + kt * 128 + col8);
                *reinterpret_cast<uint4*>(Blds + SW(row, bc)) = v;
            }
        }
        __syncthreads();
#pragma unroll
        for (int kk = 0; kk < 4; ++kk) {
            int bck = kk * 64 + lk * 16;
            bh8 b0 = *reinterpret_cast<const bh8*>(Blds + SW(0 * 16 + lr, bck));
            bh8 b1 = *reinterpret_cast<const bh8*>(Blds + SW(1 * 16 + lr, bck));
            bh8 b2 = *reinterpret_cast<const bh8*>(Blds + SW(2 * 16 + lr, bck));
            bh8 b3 = *reinterpret_cast<const bh8*>(Blds + SW(3 * 16 + lr, bck));
            bh8 a0 = *reinterpret_cast<const bh8*>(Ahi + SW(rbase + lr, bck));
            bh8 a1 = *reinterpret_cast<const bh8*>(Ahi + SW(rbase + 16 + lr, bck));
            acc00 = __builtin_amdgcn_mfma_f32_16x16x32_bf16(a0, b0, acc00, 0, 0, 0);
            acc01 = __builtin_amdgcn_mfma_f32_16x16x32_bf16(a0, b1, acc01, 0, 0, 0);
            acc02 = __builtin_amdgcn_mfma_f32_16x16x32_bf16(a0, b2, acc02, 0, 0, 0);
            acc03 = __builtin_amdgcn_mfma_f32_16x16x32_bf16(a0, b3, acc03, 0, 0, 0);
            acc10 = __builtin_amdgcn_mfma_f32_16x16x32_bf16(a1, b0, acc10, 0, 0, 0);
            acc11 = __builtin_amdgcn_mfma_f32_16x16x32_bf16(a1, b1, acc11, 0, 0, 0);
            acc12 = __builtin_amdgcn_mfma_f32_16x16x32_bf16(a1, b2, acc12, 0, 0, 0);
            acc13 = __builtin_amdgcn_mfma_f32_16x16x32_bf16(a1, b3, acc13, 0, 0, 0);
            if (kt < 6) {
                bh8 c0 = *reinterpret_cast<const bh8*>(Alo + SW(rbase + lr, bck));
                bh8 c1 = *reinterpret_cast<const bh8*>(Alo + SW(rbase + 16 + lr, bck));
                acc00 = __builtin_amdgcn_mfma_f32_16x16x32_bf16(c0, b0, acc00, 0, 0, 0);
                acc01 = __builtin_amdgcn_mfma_f32_16x16x32_bf16(c0, b1, acc01, 0, 0, 0);
                acc02 = __builtin_amdgcn_mfma_f32_16x16x32_bf16(c0, b2, acc02, 0, 0, 0);
                acc03 = __builtin_amdgcn_mfma_f32_16x16x32_bf16(c0, b3, acc03, 0, 0, 0);
                acc10 = __builtin_amdgcn_mfma_f32_16x16x32_bf16(c1, b0, acc10, 0, 0, 0);
                acc11 = __builtin_amdgcn_mfma_f32_16x16x32_bf16(c1, b1, acc11, 0, 0, 0);
                acc12 = __builtin_amdgcn_mfma_f32_16x16x32_bf16(c1, b2, acc12, 0, 0, 0);
                acc13 = __builtin_amdgcn_mfma_f32_16x16x32_bf16(c1, b3, acc13, 0, 0, 0);
            }
        }
    }

    const f4* accs[2][4] = {{&acc00, &acc01, &acc02, &acc03},
                            {&acc10, &acc11, &acc12, &acc13}};
#pragma unroll
    for (int m = 0; m < 2; ++m) {
#pragma unroll
        for (int j = 0; j < 4; ++j) {
            int gr = n0 + rbase + m * 16 + lk * 4 + j;
            if (gr >= nrows) continue;
#pragma unroll
            for (int n = 0; n < 4; ++n) {
                int col = n * 16 + lr;
                float v = (*accs[m][n])[j];
                out[(size_t)gr * 64 + col] = v * (1.f / 6.f) + mb[col];
            }
        }
    }
}

// ---------------------------------------------------------------- el / er, layers 1-2
template <int H, int D>
__global__ void k_elr_bf(const unsigned short* __restrict__ feat,
                         const float* __restrict__ al, const float* __restrict__ ar,
                         float* __restrict__ el, float* __restrict__ er, int total) {
    int gid = blockIdx.x * blockDim.x + threadIdx.x;
    if (gid >= total) return;
    int n = gid / H, h = gid - n * H;
    const uint4* f = reinterpret_cast<const uint4*>(feat + (size_t)n * (H * D) + h * D);
    const float4* a = reinterpret_cast<const float4*>(al + h * D);
    const float4* r = reinterpret_cast<const float4*>(ar + h * D);
    float sl = 0.f, sr = 0.f;
#pragma unroll
    for (int j = 0; j < D / 8; ++j) {
        uint4 v = f[j];
        float4 a0 = a[2 * j], a1 = a[2 * j + 1];
        float4 r0 = r[2 * j], r1 = r[2 * j + 1];
        float x0 = blo(v.x), x1 = bhi(v.x), x2 = blo(v.y), x3 = bhi(v.y);
        float x4 = blo(v.z), x5 = bhi(v.z), x6 = blo(v.w), x7 = bhi(v.w);
        sl += x0 * a0.x + x1 * a0.y + x2 * a0.z + x3 * a0.w +
              x4 * a1.x + x5 * a1.y + x6 * a1.z + x7 * a1.w;
        sr += x0 * r0.x + x1 * r0.y + x2 * r0.z + x3 * r0.w +
              x4 * r1.x + x5 * r1.y + x6 * r1.z + x7 * r1.w;
    }
    el[gid] = sl;
    er[gid] = sr;
}

// ---------------------------------------------------------------- el / er, layer 3
__global__ void k_elr3(const unsigned short* __restrict__ h2b,
                       const float* __restrict__ al3c, const float* __restrict__ ar3c,
                       float* __restrict__ el, float* __restrict__ er, int total) {
    int gid = blockIdx.x * blockDim.x + threadIdx.x;
    if (gid >= total) return;
    int n = gid / 6, h = gid - n * 6;
    const uint4* f = reinterpret_cast<const uint4*>(h2b + (size_t)n * 128);
    const float4* a = reinterpret_cast<const float4*>(al3c + h * 128);
    const float4* r = reinterpret_cast<const float4*>(ar3c + h * 128);
    float sl = 0.f, sr = 0.f;
#pragma unroll
    for (int j = 0; j < 16; ++j) {
        uint4 v = f[j];
        float4 a0 = a[2 * j], a1 = a[2 * j + 1];
        float4 r0 = r[2 * j], r1 = r[2 * j + 1];
        float x0 = blo(v.x), x1 = bhi(v.x), x2 = blo(v.y), x3 = bhi(v.y);
        float x4 = blo(v.z), x5 = bhi(v.z), x6 = blo(v.w), x7 = bhi(v.w);
        sl += x0 * a0.x + x1 * a0.y + x2 * a0.z + x3 * a0.w +
              x4 * a1.x + x5 * a1.y + x6 * a1.z + x7 * a1.w;
        sr += x0 * r0.x + x1 * r0.y + x2 * r0.z + x3 * r0.w +
              x4 * r1.x + x5 * r1.y + x6 * r1.z + x7 * r1.w;
    }
    el[gid] = sl;
    er[gid] = sr;
}

// ---------------------------------------------------------------- aggregation, layers 1-2
template <bool HASRES, bool WRITEF32>
__global__ __launch_bounds__(256) void k_aggr128d(
    const unsigned short* __restrict__ feat, const int2* __restrict__ csr2,
    const int* __restrict__ offs, const unsigned short* __restrict__ aw,
    const float* __restrict__ inv4, const float* __restrict__ bias,
    const float* __restrict__ resf, unsigned short* __restrict__ outb,
    float* __restrict__ outf, int nnodes) {
    int node = blockIdx.x * 4 + (threadIdx.x >> 6);
    if (node >= nnodes) return;
    int l = threadIdx.x & 63;
    int half = l >> 5;
    int ll = l & 31;
    int h = ll >> 3;
    int o0 = offs[node], o1 = offs[node + 1];
    float acc0 = 0.f, acc1 = 0.f, acc2 = 0.f, acc3 = 0.f;
    int nt = (o1 - o0 + 1) >> 1;
#pragma unroll 4
    for (int t = 0; t < nt; ++t) {
        int ei = o0 + 2 * t + half;
        int pos = (ei < o1) ? ei : EDGES;      // dummy slot: w == 0
        uint2 wu = *reinterpret_cast<const uint2*>(aw + (size_t)pos * 4);
        unsigned uw = (h & 2) ? wu.y : wu.x;
        float w = (h & 1) ? bhi(uw) : blo(uw);
        int sidx = csr2[pos].x;
        uint2 u = *reinterpret_cast<const uint2*>(feat + (size_t)sidx * 128 + 4 * ll);
        acc0 = fmaf(w, blo(u.x), acc0);
        acc1 = fmaf(w, bhi(u.x), acc1);
        acc2 = fmaf(w, blo(u.y), acc2);
        acc3 = fmaf(w, bhi(u.y), acc3);
    }
    acc0 += __shfl_xor(acc0, 32);
    acc1 += __shfl_xor(acc1, 32);
    acc2 += __shfl_xor(acc2, 32);
    acc3 += __shfl_xor(acc3, 32);
    float inv = inv4[(size_t)node * 4 + h];
    int f = 4 * ll;
    float4 bi = *reinterpret_cast<const float4*>(bias + f);
    float r0 = acc0 * inv + bi.x;
    float r1 = acc1 * inv + bi.y;
    float r2 = acc2 * inv + bi.z;
    float r3 = acc3 * inv + bi.w;
    if (HASRES) {
        float4 rv = *reinterpret_cast<const float4*>(resf + (size_t)node * 128 + f);
        r0 += rv.x; r1 += rv.y; r2 += rv.z; r3 += rv.w;
    }
    r0 = (r0 > 0.f) ? r0 : (__expf(r0) - 1.f);
    r1 = (r1 > 0.f) ? r1 : (__expf(r1) - 1.f);
    r2 = (r2 > 0.f) ? r2 : (__expf(r2) - 1.f);
    r3 = (r3 > 0.f) ? r3 : (__expf(r3) - 1.f);
    if (half == 0) {
        unsigned u0 = f2bf(r0) | (f2bf(r1) << 16);
        unsigned u1 = f2bf(r2) | (f2bf(r3) << 16);
        *reinterpret_cast<uint2*>(outb + (size_t)node * 128 + f) = make_uint2(u0, u1);
        if (WRITEF32)
            *reinterpret_cast<float4*>(outf + (size_t)node * 128 + f) =
                make_float4(r0, r1, r2, r3);
    }
}

// ---------------------------------------------------------------- aggregation, layer 3 (z-form)
__global__ __launch_bounds__(256) void k_aggrZ3(
    const unsigned short* __restrict__ h2b, const int2* __restrict__ csr2,
    const int* __restrict__ offs, const unsigned short* __restrict__ aw6,
    const float* __restrict__ inv6, float* __restrict__ zf, int nnodes) {
    int node = blockIdx.x * 4 + (threadIdx.x >> 6);
    if (node >= nnodes) return;
    int l = threadIdx.x & 63;
    int half = l >> 5;
    int ll = l & 31;
    float acc[6][4];
#pragma unroll
    for (int h = 0; h < 6; ++h)
#pragma unroll
        for (int j = 0; j < 4; ++j) acc[h][j] = 0.f;
    int o0 = offs[node], o1 = offs[node + 1];
    int nt = (o1 - o0 + 1) >> 1;
    const unsigned char* awb = reinterpret_cast<const unsigned char*>(aw6);
#pragma unroll 4
    for (int t = 0; t < nt; ++t) {
        int ei = o0 + 2 * t + half;
        int pos = (ei < o1) ? ei : EDGES;      // dummy slot: w == 0
        const unsigned char* wb = awb + (size_t)pos * 12;
        unsigned w01 = *reinterpret_cast<const unsigned*>(wb + 0);
        unsigned w23 = *reinterpret_cast<const unsigned*>(wb + 4);
        unsigned w45 = *reinterpret_cast<const unsigned*>(wb + 8);
        float wv[6] = {blo(w01), bhi(w01), blo(w23), bhi(w23), blo(w45), bhi(w45)};
        int sidx = csr2[pos].x;
        uint2 u = *reinterpret_cast<const uint2*>(h2b + (size_t)sidx * 128 + 4 * ll);
        float f0 = blo(u.x), f1 = bhi(u.x), f2 = blo(u.y), f3 = bhi(u.y);
#pragma unroll
        for (int h = 0; h < 6; ++h) {
            acc[h][0] = fmaf(wv[h], f0, acc[h][0]);
            acc[h][1] = fmaf(wv[h], f1, acc[h][1]);
            acc[h][2] = fmaf(wv[h], f2, acc[h][2]);
            acc[h][3] = fmaf(wv[h], f3, acc[h][3]);
        }
    }
#pragma unroll
    for (int h = 0; h < 6; ++h)
#pragma unroll
        for (int j = 0; j < 4; ++j) acc[h][j] += __shfl_xor(acc[h][j], 32);
    if (half == 0) {
        float2 i01 = *reinterpret_cast<const float2*>(inv6 + (size_t)node * 6 + 0);
        float2 i23 = *reinterpret_cast<const float2*>(inv6 + (size_t)node * 6 + 2);
        float2 i45 = *reinterpret_cast<const float2*>(inv6 + (size_t)node * 6 + 4);
        float iv[6] = {i01.x, i01.y, i23.x, i23.y, i45.x, i45.y};
#pragma unroll
        for (int h = 0; h < 6; ++h) {
            *reinterpret_cast<float4*>(zf + (size_t)node * 768 + h * 128 + 4 * ll) =
                make_float4(acc[h][0] * iv[h], acc[h][1] * iv[h],
                            acc[h][2] * iv[h], acc[h][3] * iv[h]);
        }
    }
}

// ---------------------------------------------------------------- launch
extern "C" void kernel_launch(void* const* d_in, const int* in_sizes, int n_in,
                              void* d_out, int out_size, void* d_ws, size_t ws_size,
                              hipStream_t stream) {
    const float* x     = (const float*)d_in[0];
    const int*   src   = (const int*)d_in[1];
    const int*   dst   = (const int*)d_in[2];
    const float* W1    = (const float*)d_in[3];
    const float* al1   = (const float*)d_in[4];
    const float* ar1   = (const float*)d_in[5];
    const float* b1    = (const float*)d_in[6];
    const float* W2    = (const float*)d_in[7];
    const float* al2   = (const float*)d_in[8];
    const float* ar2   = (const float*)d_in[9];
    const float* b2    = (const float*)d_in[10];
    const float* W3    = (const float*)d_in[11];
    const float* al3   = (const float*)d_in[12];
    const float* ar3   = (const float*)d_in[13];
    const float* b3    = (const float*)d_in[14];
    const float* Wres3 = (const float*)d_in[15];
    float* out = (float*)d_out;

    const int N = NODES, E = EDGES;
    const int NB = (N + 255) / 256;

    char*  ws = (char*)d_ws;
    size_t o  = 0;
    auto alloc = [&](size_t bytes) {
        size_t r = o;
        o += (bytes + 255) & ~(size_t)255;
        return r;
    };
    // persistent (~33 MB)
    int*            offs  = (int*)(ws + alloc((size_t)(N + 1) * 4));
    int*            cnt   = (int*)(ws + alloc((size_t)N * 4));
    int2*           csr2  = (int2*)(ws + alloc((size_t)(E + 1) * 8));
    float*          el    = (float*)(ws + alloc((size_t)N * 6 * 4));
    float*          er    = (float*)(ws + alloc((size_t)N * 6 * 4));
    unsigned short* aw    = (unsigned short*)(ws + alloc((size_t)(E + 1) * 6 * 2));
    float*          inv   = (float*)(ws + alloc((size_t)N * 6 * 4));     // inv4/inv6
    unsigned short* h2b   = (unsigned short*)(ws + alloc((size_t)N * 128 * 2));
    unsigned short* w1t   = (unsigned short*)(ws + alloc((size_t)128 * 128 * 2));
    unsigned short* w2t   = (unsigned short*)(ws + alloc((size_t)128 * 128 * 2));
    unsigned short* bt2   = (unsigned short*)(ws + alloc((size_t)64 * 896 * 2));
    float*          al3c  = (float*)(ws + alloc((size_t)768 * 4));
    float*          ar3c  = (float*)(ws + alloc((size_t)768 * 4));
    float*          mb    = (float*)(ws + alloc((size_t)64 * 4));
    int*            bsum  = (int*)(ws + alloc((size_t)256 * 4));
    int*            bpre  = (int*)(ws + alloc((size_t)256 * 4));
    // union region (153.6 MB): L1/2 transients + rank alias zf (disjoint lifetimes)
    char* U = ws + alloc((size_t)N * 768 * 4);
    unsigned short* xb    = (unsigned short*)(U);                        // 12.8M
    unsigned short* featb = (unsigned short*)(U + (size_t)N * 128 * 2);  // 12.8M
    unsigned short* h1b   = (unsigned short*)(U + (size_t)N * 256 * 2);  // 12.8M
    float*          h1f   = (float*)(U + (size_t)N * 384 * 2);           // 25.6M (ends 64M)
    int*            rank  = (int*)(U + (size_t)64 * 1024 * 1024);        // 3.2M @64M, dead before zf
    float*          zf    = (float*)(U);                                 // 153.6M (layer 3)

    const int gE = (E + 255) / 256;
    const int g4 = (N * 4 + 255) / 256;
    const int g6 = (N * 6 + 255) / 256;
    const int gN = (N + 255) / 256;
    const int gA = (N + 3) / 4;
    const int gG = (N + 63) / 64;
    const int gT = (N + 127) / 128;

    // ---- prep
    k_cast<<<(N * 128 / 4 + 255) / 256, 256, 0, stream>>>(x, xb, N * 128 / 4);
    k_prepw<<<(128 * 128 + 255) / 256, 256, 0, stream>>>(W1, w1t, 128);
    k_prepw<<<(128 * 128 + 255) / 256, 256, 0, stream>>>(W2, w2t, 128);
    k_prep_bt2<<<(64 * 896 + 255) / 256, 256, 0, stream>>>(W3, Wres3, bt2);
    k_prep_alr3<<<6, 256, 0, stream>>>(W3, al3, ar3, al3c, ar3c);
    k_prep_mb<<<1, 64, 0, stream>>>(b3, mb);

    // ---- dummy edge slot: csr2[E]={0,0}; aw zeroed at both layouts' index E
    hipMemsetAsync(csr2 + E, 0, 8, stream);
    hipMemsetAsync((char*)aw + (size_t)E * 8, 0, 8, stream);    // ew4 layout dummy
    hipMemsetAsync((char*)aw + (size_t)E * 12, 0, 12, stream);  // ew6 layout dummy

    // ---- CSR by dst: hist+rank (atomic), parallel scan, atomic-free fill
    hipMemsetAsync(cnt, 0, (size_t)N * 4, stream);
    k_hist2<<<gE, 256, 0, stream>>>(dst, cnt, rank, E);
    k_bsum<<<NB, 256, 0, stream>>>(cnt, bsum, N);
    k_bscan<<<1, 256, 0, stream>>>(bsum, bpre, NB);
    k_offs<<<NB, 256, 0, stream>>>(cnt, bpre, offs, N, E);
    k_fill2<<<gE, 256, 0, stream>>>(src, dst, offs, rank, csr2, E);

    // ---- layer 1: x -> h1
    k_mgemm128<<<gG, 256, 0, stream>>>(xb, w1t, featb, N);
    k_elr_bf<4, 32><<<g4, 256, 0, stream>>>(featb, al1, ar1, el, er, N * 4);
    k_ew4<<<gE, 256, 0, stream>>>(csr2, el, er, aw, E);
    k_denom4<<<gN, 256, 0, stream>>>(aw, offs, inv, N);
    k_aggr128d<false, true><<<gA, 256, 0, stream>>>(featb, csr2, offs, aw, inv, b1,
                                                    nullptr, h1b, h1f, N);

    // ---- layer 2: h1 -> h2
    k_mgemm128<<<gG, 256, 0, stream>>>(h1b, w2t, featb, N);
    k_elr_bf<4, 32><<<g4, 256, 0, stream>>>(featb, al2, ar2, el, er, N * 4);
    k_ew4<<<gE, 256, 0, stream>>>(csr2, el, er, aw, E);
    k_denom4<<<gN, 256, 0, stream>>>(aw, offs, inv, N);
    k_aggr128d<true, false><<<gA, 256, 0, stream>>>(featb, csr2, offs, aw, inv, b2,
                                                    h1f, h2b, nullptr, N);

    // ---- layer 3: weights -> z (f32) -> tail GEMM (128-row tiles, R12 version)
    k_elr3<<<g6, 256, 0, stream>>>(h2b, al3c, ar3c, el, er, N * 6);
    k_ew6<<<gE, 256, 0, stream>>>(csr2, el, er, aw, E);
    k_denom6<<<gN, 256, 0, stream>>>(aw, offs, inv, N);
    k_aggrZ3<<<gA, 256, 0, stream>>>(h2b, csr2, offs, aw, inv, zf, N);
    k_mtail3<<<gT, 256, 0, stream>>>(zf, h2b, bt2, mb, out, N);
}